// Round 6
// baseline (214.240 us; speedup 1.0000x reference)
//
#include <hip/hip_runtime.h>
#include <math.h>

#define BATCH   2048
#define NROWS   4096   // 2*BATCH
#define LATENT  2048
#define PROJ    256
#define TEMP_INV 2.0f      // 1/0.5
#define BN_EPS  1e-5f
#define COS_EPS 1e-8f

typedef __bf16 bf16x8 __attribute__((ext_vector_type(8)));
typedef float  f32x4  __attribute__((ext_vector_type(4)));

__device__ __forceinline__ unsigned short f2bf(float f) {
    union { float f; unsigned int u; } c; c.f = f;
    return (unsigned short)((c.u + 0x7FFFu + ((c.u >> 16) & 1u)) >> 16);
}
__device__ __forceinline__ float bf2f(unsigned short h) {
    union { unsigned int u; float f; } c; c.u = ((unsigned int)h) << 16;
    return c.f;
}

// async global->LDS, 16 bytes per lane. LDS dest is wave-uniform base + lane*16.
__device__ __forceinline__ void gl_lds16(const unsigned short* g, unsigned short* l) {
    __builtin_amdgcn_global_load_lds(
        (__attribute__((address_space(1))) void*)g,
        (__attribute__((address_space(3))) void*)l, 16, 0, 0);
}

// LDS element offset of (row R, k-chunk lk) under the granule XOR swizzle.
// Granule (R, c) is stored at slot c ^ ((R>>1)&3) within row R's 4 slots.
__device__ __forceinline__ int swz(int R, int lk) {
    return R * 32 + ((lk ^ ((R >> 1) & 3)) << 3);
}

// ---------------------------------------------------------------------------
// Fused fp32->bf16 convert of all four inputs into one contiguous bf16 region
// [Hb(h_i|h_j) | W1b | W2b]. 4 floats/thread.
// ---------------------------------------------------------------------------
#define G1 1048576   // h_i float4-groups
#define G2 2097152
#define G3 3145728
#define G4 3276800
__global__ __launch_bounds__(256) void cvt_all_kernel(
    const float* __restrict__ h_i, const float* __restrict__ h_j,
    const float* __restrict__ W1,  const float* __restrict__ W2,
    unsigned short* __restrict__ dst)
{
    int i = blockIdx.x * 256 + threadIdx.x;
    if (i >= G4) return;
    const float* src; int off;
    if (i < G1)      { src = h_i; off = i; }
    else if (i < G2) { src = h_j; off = i - G1; }
    else if (i < G3) { src = W1;  off = i - G2; }
    else             { src = W2;  off = i - G3; }
    float4 v = reinterpret_cast<const float4*>(src)[off];
    ushort4 o;
    o.x = f2bf(v.x); o.y = f2bf(v.y); o.z = f2bf(v.z); o.w = f2bf(v.w);
    reinterpret_cast<ushort4*>(dst)[i] = o;
}

// ---------------------------------------------------------------------------
// Double-buffered MFMA K-loop. 256 threads = 4 waves in 2x2.
// BM=WM*32, BN=WN*32, BK=32. Operands row-major [rows][KSTRIDE] bf16.
// As/Bs are 2*BM*32 / 2*BN*32 elems (two buffers each). Per iter:
//   barrier (drains PREVIOUS iter's global_load_lds -> they had a full
//   compute phase in flight) -> issue loads for k+32 into other buffer ->
//   ds_read + MFMA on current buffer.
// ---------------------------------------------------------------------------
template<int KSTRIDE, int KLEN, int WM, int WN>
__device__ __forceinline__ void mfma_loop_db(
    const unsigned short* __restrict__ Ab,
    const unsigned short* __restrict__ Bb,
    unsigned short* As, unsigned short* Bs,
    f32x4 acc[WM][WN], int tid)
{
    constexpr int BM = WM * 32;
    constexpr int BN = WN * 32;
    const int wid = tid >> 6, lane = tid & 63;
    const int mblk = (wid >> 1) * (WM * 16);
    const int nblk = (wid & 1) * (WN * 16);
    const int lr = lane & 15, lk = lane >> 4;

    // prologue: stage k0=0 into buffer 0
    #pragma unroll
    for (int u = 0; u < BM / 64; ++u) {
        int li = u * 256 + tid;
        int r = li >> 2, c = (li & 3) ^ ((li >> 3) & 3);
        gl_lds16(Ab + (size_t)r * KSTRIDE + c * 8, As + li * 8);
    }
    #pragma unroll
    for (int u = 0; u < BN / 64; ++u) {
        int li = u * 256 + tid;
        int r = li >> 2, c = (li & 3) ^ ((li >> 3) & 3);
        gl_lds16(Bb + (size_t)r * KSTRIDE + c * 8, Bs + li * 8);
    }

    for (int k0 = 0; k0 < KLEN; k0 += 32) {
        const int cur = (k0 >> 5) & 1;
        unsigned short* Ac = As + cur * (BM * 32);
        unsigned short* Bc = Bs + cur * (BN * 32);
        __syncthreads();   // drains loads issued last iter (overlapped w/ compute)
        if (k0 + 32 < KLEN) {
            unsigned short* An = As + (cur ^ 1) * (BM * 32);
            unsigned short* Bn = Bs + (cur ^ 1) * (BN * 32);
            #pragma unroll
            for (int u = 0; u < BM / 64; ++u) {
                int li = u * 256 + tid;
                int r = li >> 2, c = (li & 3) ^ ((li >> 3) & 3);
                gl_lds16(Ab + (size_t)r * KSTRIDE + k0 + 32 + c * 8, An + li * 8);
            }
            #pragma unroll
            for (int u = 0; u < BN / 64; ++u) {
                int li = u * 256 + tid;
                int r = li >> 2, c = (li & 3) ^ ((li >> 3) & 3);
                gl_lds16(Bb + (size_t)r * KSTRIDE + k0 + 32 + c * 8, Bn + li * 8);
            }
        }
        bf16x8 af[WM], bv[WN];
        #pragma unroll
        for (int i = 0; i < WM; ++i)
            af[i] = *reinterpret_cast<const bf16x8*>(Ac + swz(mblk + i * 16 + lr, lk));
        #pragma unroll
        for (int j = 0; j < WN; ++j)
            bv[j] = *reinterpret_cast<const bf16x8*>(Bc + swz(nblk + j * 16 + lr, lk));
        #pragma unroll
        for (int i = 0; i < WM; ++i)
            #pragma unroll
            for (int j = 0; j < WN; ++j)
                acc[i][j] = __builtin_amdgcn_mfma_f32_16x16x32_bf16(af[i], bv[j], acc[i][j], 0, 0, 0);
    }
}

// ---------------------------------------------------------------------------
// GEMM1: X[m][n] = sum_k H[m][k]*W1[n][k]  (M=4096, N=2048, K=2048)
// BM=128 x BN=128 -> 512 blocks. Epilogue: bf16 X store + fused BN column
// stats (sum, sumsq) from fp32 accumulators.
// ---------------------------------------------------------------------------
__global__ __launch_bounds__(256) void gemm1_mfma(
    const unsigned short* __restrict__ Hb, const unsigned short* __restrict__ W1b,
    unsigned short* __restrict__ Xb, float* __restrict__ sums, float* __restrict__ sumsqs)
{
    __shared__ __align__(16) unsigned short As[2 * 128 * 32];
    __shared__ __align__(16) unsigned short Bs[2 * 128 * 32];
    const int tid = threadIdx.x;
    const int m0 = blockIdx.y * 128, n0 = blockIdx.x * 128;
    f32x4 zero = {0.f, 0.f, 0.f, 0.f};
    f32x4 acc[4][4];
    #pragma unroll
    for (int i = 0; i < 4; ++i)
        #pragma unroll
        for (int j = 0; j < 4; ++j) acc[i][j] = zero;
    mfma_loop_db<LATENT, LATENT, 4, 4>(Hb + (size_t)m0 * LATENT, W1b + (size_t)n0 * LATENT,
                                       As, Bs, acc, tid);
    const int wid = tid >> 6, lane = tid & 63;
    const int mblk = (wid >> 1) * 64, nblk = (wid & 1) * 64;
    const int lr = lane & 15, lq = lane >> 4;
    const int half = m0 >> 11;   // m0/BATCH (tile is entirely in one half)
    #pragma unroll
    for (int j = 0; j < 4; ++j) {
        float s = 0.f, q = 0.f;
        #pragma unroll
        for (int i = 0; i < 4; ++i)
            #pragma unroll
            for (int r = 0; r < 4; ++r) {
                float v = acc[i][j][r];
                s += v; q += v * v;
                int row = m0 + mblk + i * 16 + lq * 4 + r;
                int col = n0 + nblk + j * 16 + lr;
                Xb[(size_t)row * LATENT + col] = f2bf(v);
            }
        // reduce over lq (lanes ^16, ^32): covers this wave's 64 rows
        s += __shfl_xor(s, 16, 64);  q += __shfl_xor(q, 16, 64);
        s += __shfl_xor(s, 32, 64);  q += __shfl_xor(q, 32, 64);
        if (lq == 0) {
            int col = n0 + nblk + j * 16 + lr;
            atomicAdd(&sums[half * LATENT + col], s);
            atomicAdd(&sumsqs[half * LATENT + col], q);
        }
    }
}

// ---------------------------------------------------------------------------
// BN scale/shift computed inline from stats + ReLU, in-place on bf16 X.
// One block per row (256 thr x 8 elems = 2048 cols).
// ---------------------------------------------------------------------------
__global__ __launch_bounds__(256) void bnrelu_kernel(
    unsigned short* __restrict__ Xb, const float* __restrict__ sums,
    const float* __restrict__ sumsqs, const float* __restrict__ gamma,
    const float* __restrict__ beta)
{
    const int row = blockIdx.x;
    const int half = row >> 11;
    const int col = threadIdx.x * 8;
    size_t idx = (size_t)row * LATENT + col;
    ushort4 a = *reinterpret_cast<const ushort4*>(Xb + idx);
    ushort4 b = *reinterpret_cast<const ushort4*>(Xb + idx + 4);
    const float* S = sums + half * LATENT + col;
    const float* Q = sumsqs + half * LATENT + col;
    float4 s0 = *reinterpret_cast<const float4*>(S);
    float4 s1 = *reinterpret_cast<const float4*>(S + 4);
    float4 q0 = *reinterpret_cast<const float4*>(Q);
    float4 q1 = *reinterpret_cast<const float4*>(Q + 4);
    float4 g0 = *reinterpret_cast<const float4*>(gamma + col);
    float4 g1 = *reinterpret_cast<const float4*>(gamma + col + 4);
    float4 e0 = *reinterpret_cast<const float4*>(beta + col);
    float4 e1 = *reinterpret_cast<const float4*>(beta + col + 4);
    ushort4 oa, ob;
    #define BN1(x, sv, qv, gv, ev, o) { \
        float mu = (sv) * (1.0f / BATCH); \
        float var = (qv) * (1.0f / BATCH) - mu * mu; \
        float sc = (gv) * rsqrtf(var + BN_EPS); \
        float sh = (ev) - mu * sc; \
        o = f2bf(fmaxf(fmaf(bf2f(x), sc, sh), 0.f)); }
    BN1(a.x, s0.x, q0.x, g0.x, e0.x, oa.x) BN1(a.y, s0.y, q0.y, g0.y, e0.y, oa.y)
    BN1(a.z, s0.z, q0.z, g0.z, e0.z, oa.z) BN1(a.w, s0.w, q0.w, g0.w, e0.w, oa.w)
    BN1(b.x, s1.x, q1.x, g1.x, e1.x, ob.x) BN1(b.y, s1.y, q1.y, g1.y, e1.y, ob.y)
    BN1(b.z, s1.z, q1.z, g1.z, e1.z, ob.z) BN1(b.w, s1.w, q1.w, g1.w, e1.w, ob.w)
    #undef BN1
    *reinterpret_cast<ushort4*>(Xb + idx) = oa;
    *reinterpret_cast<ushort4*>(Xb + idx + 4) = ob;
}

// ---------------------------------------------------------------------------
// GEMM2 split-K=4: Zp[kc][m][n] = sum_{k in chunk} Xb[m][k]*W2[n][k]
// BM=128 x BN=64 x KC=512 -> 512 blocks (2/CU).
// ---------------------------------------------------------------------------
__global__ __launch_bounds__(256) void gemm2_mfma(
    const unsigned short* __restrict__ Xb, const unsigned short* __restrict__ W2b,
    float* __restrict__ Zp)
{
    __shared__ __align__(16) unsigned short As[2 * 128 * 32];
    __shared__ __align__(16) unsigned short Bs[2 * 64 * 32];
    const int tid = threadIdx.x;
    const int m0 = blockIdx.y * 128, n0 = blockIdx.x * 64, kc = blockIdx.z;
    f32x4 zero = {0.f, 0.f, 0.f, 0.f};
    f32x4 acc[4][2];
    #pragma unroll
    for (int i = 0; i < 4; ++i) { acc[i][0] = zero; acc[i][1] = zero; }
    mfma_loop_db<LATENT, 512, 4, 2>(Xb + (size_t)m0 * LATENT + kc * 512,
                                    W2b + (size_t)n0 * LATENT + kc * 512, As, Bs, acc, tid);
    float* Zk = Zp + (size_t)kc * NROWS * PROJ;
    const int wid = tid >> 6, lane = tid & 63;
    const int mblk = (wid >> 1) * 64, nblk = (wid & 1) * 32;
    const int lr = lane & 15, lq = lane >> 4;
    #pragma unroll
    for (int i = 0; i < 4; ++i)
        #pragma unroll
        for (int j = 0; j < 2; ++j)
            #pragma unroll
            for (int r = 0; r < 4; ++r) {
                int row = m0 + mblk + i * 16 + lq * 4 + r;
                int col = n0 + nblk + j * 16 + lr;
                Zk[(size_t)row * PROJ + col] = acc[i][j][r];
            }
}

// ---------------------------------------------------------------------------
// Sum 4 K-partials + b2, L2-normalize row -> bf16 ZNb. One wave per row.
// ---------------------------------------------------------------------------
__global__ __launch_bounds__(256) void rownorm_kernel(
    const float* __restrict__ Zp, const float* __restrict__ b2,
    unsigned short* __restrict__ ZNb)
{
    const int wave = threadIdx.x >> 6;
    const int lane = threadIdx.x & 63;
    const int row = blockIdx.x * 4 + wave;
    float v[4];
    float sq = 0.f;
    #pragma unroll
    for (int i = 0; i < 4; ++i) {
        int col = lane + i * 64;
        float t = b2[col];
        #pragma unroll
        for (int c = 0; c < 4; ++c)
            t += Zp[(size_t)c * NROWS * PROJ + (size_t)row * PROJ + col];
        v[i] = t;
        sq += t * t;
    }
    #pragma unroll
    for (int off = 32; off > 0; off >>= 1) sq += __shfl_xor(sq, off, 64);
    float inv = 1.0f / fmaxf(sqrtf(sq), COS_EPS);
    #pragma unroll
    for (int i = 0; i < 4; ++i)
        ZNb[(size_t)row * PROJ + lane + i * 64] = f2bf(v[i] * inv);
}

// ---------------------------------------------------------------------------
// sim tile via MFMA + fused exp/rowsum/diag/pos. K=PROJ=256.
// ---------------------------------------------------------------------------
__global__ __launch_bounds__(256) void simlse_mfma(
    const unsigned short* __restrict__ ZNb, float* __restrict__ rowsum,
    float* __restrict__ dgA, float* __restrict__ posA)
{
    __shared__ __align__(16) unsigned short As[2 * 128 * 32];
    __shared__ __align__(16) unsigned short Bs[2 * 128 * 32];
    const int tid = threadIdx.x;
    const int r0 = blockIdx.y * 128, j0 = blockIdx.x * 128;
    f32x4 zero = {0.f, 0.f, 0.f, 0.f};
    f32x4 acc[4][4];
    #pragma unroll
    for (int i = 0; i < 4; ++i)
        #pragma unroll
        for (int j = 0; j < 4; ++j) acc[i][j] = zero;
    mfma_loop_db<PROJ, PROJ, 4, 4>(ZNb + (size_t)r0 * PROJ, ZNb + (size_t)j0 * PROJ,
                                   As, Bs, acc, tid);
    const int wid = tid >> 6, lane = tid & 63;
    const int mblk = (wid >> 1) * 64, nblk = (wid & 1) * 64;
    const int lr = lane & 15, lq = lane >> 4;
    #pragma unroll
    for (int i = 0; i < 4; ++i)
        #pragma unroll
        for (int r = 0; r < 4; ++r) {
            int R = r0 + mblk + i * 16 + lq * 4 + r;
            int P = (R < BATCH) ? R + BATCH : R - BATCH;
            float t = 0.f;
            #pragma unroll
            for (int j = 0; j < 4; ++j) {
                int J = j0 + nblk + j * 16 + lr;
                float s = acc[i][j][r] * TEMP_INV;
                float e = __expf(s);
                t += e;
                if (J == R) dgA[R] = e;     // unique writer
                if (J == P) posA[R] = s;    // unique writer
            }
            t += __shfl_xor(t, 1, 64);
            t += __shfl_xor(t, 2, 64);
            t += __shfl_xor(t, 4, 64);
            t += __shfl_xor(t, 8, 64);
            if (lr == 0) atomicAdd(&rowsum[R], t);
        }
}

// loss = (1/N) * sum_r [ log(rowsum_r - diag_r) - pos_r ]
__global__ __launch_bounds__(256) void loss_kernel(
    const float* __restrict__ rowsum, const float* __restrict__ dgA,
    const float* __restrict__ posA, float* __restrict__ out)
{
    __shared__ float red[256];
    float s = 0.f;
    for (int r = threadIdx.x; r < NROWS; r += 256)
        s += logf(rowsum[r] - dgA[r]) - posA[r];
    red[threadIdx.x] = s;
    __syncthreads();
    for (int off = 128; off > 0; off >>= 1) {
        if (threadIdx.x < off) red[threadIdx.x] += red[threadIdx.x + off];
        __syncthreads();
    }
    if (threadIdx.x == 0) out[0] = red[0] * (1.0f / NROWS);
}

// ---------------------------------------------------------------------------
extern "C" void kernel_launch(void* const* d_in, const int* in_sizes, int n_in,
                              void* d_out, int out_size, void* d_ws, size_t ws_size,
                              hipStream_t stream)
{
    const float* h_i   = (const float*)d_in[0];
    const float* h_j   = (const float*)d_in[1];
    const float* W1    = (const float*)d_in[2];
    const float* gamma = (const float*)d_in[3];
    const float* beta  = (const float*)d_in[4];
    const float* W2    = (const float*)d_in[5];
    const float* b2    = (const float*)d_in[6];
    float* out = (float*)d_out;

    // workspace (~62 MB)
    float* Zp     = (float*)d_ws;                        // 4 * 4096*256 fp32
    float* sums   = Zp + (size_t)4 * NROWS * PROJ;       // 4096
    float* sumsqs = sums + 2 * LATENT;                   // 4096
    float* rowsum = sumsqs + 2 * LATENT;                 // 4096
    float* dgA    = rowsum + NROWS;                      // 4096
    float* posA   = dgA + NROWS;                         // 4096
    unsigned short* Hb  = (unsigned short*)(posA + NROWS);   // 4096*2048 bf16
    unsigned short* W1b = Hb + (size_t)NROWS * LATENT;       // 2048*2048
    unsigned short* W2b = W1b + (size_t)LATENT * LATENT;     // 256*2048
    unsigned short* Xb  = W2b + (size_t)PROJ * LATENT;       // 4096*2048
    unsigned short* ZNb = Xb + (size_t)NROWS * LATENT;       // 4096*256

    // zero atomic accumulators (sums, sumsqs, rowsum contiguous = 12288 floats)
    hipMemsetAsync(sums, 0, (size_t)(4 * LATENT + NROWS) * sizeof(float), stream);

    cvt_all_kernel<<<(G4 + 255) / 256, 256, 0, stream>>>(h_i, h_j, W1, W2, Hb);
    gemm1_mfma<<<dim3(LATENT / 128, NROWS / 128), 256, 0, stream>>>(Hb, W1b, Xb, sums, sumsqs);
    bnrelu_kernel<<<NROWS, 256, 0, stream>>>(Xb, sums, sumsqs, gamma, beta);
    gemm2_mfma<<<dim3(PROJ / 64, NROWS / 128, 4), 256, 0, stream>>>(Xb, W2b, Zp);
    rownorm_kernel<<<NROWS / 4, 256, 0, stream>>>(Zp, b2, ZNb);
    simlse_mfma<<<dim3(NROWS / 128, NROWS / 128), 256, 0, stream>>>(ZNb, rowsum, dgA, posA);
    loss_kernel<<<1, 256, 0, stream>>>(rowsum, dgA, posA, out);
}

// Round 7
// 190.993 us; speedup vs baseline: 1.1217x; 1.1217x over previous
//
#include <hip/hip_runtime.h>
#include <hip/hip_fp8.h>
#include <math.h>

#define BATCH   2048
#define NROWS   4096   // 2*BATCH
#define LATENT  2048
#define PROJ    256
#define TEMP_INV 2.0f      // 1/0.5
#define BN_EPS  1e-5f
#define COS_EPS 1e-8f
#define W1SCALE 32.0f      // W1 pre-scaled into e4m3 normal range
#define W1INV   (1.0f / 32.0f)

typedef __bf16 bf16x8 __attribute__((ext_vector_type(8)));
typedef float  f32x4  __attribute__((ext_vector_type(4)));
typedef long   i64;

__device__ __forceinline__ unsigned short f2bf(float f) {
    union { float f; unsigned int u; } c; c.f = f;
    return (unsigned short)((c.u + 0x7FFFu + ((c.u >> 16) & 1u)) >> 16);
}
__device__ __forceinline__ float bf2f(unsigned short h) {
    union { unsigned int u; float f; } c; c.u = ((unsigned int)h) << 16;
    return c.f;
}
__device__ __forceinline__ unsigned char f2fp8(float f) {
    __hip_fp8_e4m3 t(f);
    return (unsigned char)t.__x;
}

// async global->LDS, 16 bytes per lane. LDS dest is wave-uniform base + lane*16.
__device__ __forceinline__ void gl_lds16(const void* g, void* l) {
    __builtin_amdgcn_global_load_lds(
        (const __attribute__((address_space(1))) void*)g,
        (__attribute__((address_space(3))) void*)l, 16, 0, 0);
}

// bf16 LDS element offset of (row R, k-chunk lk); granule (R,c) at slot c^((R>>1)&3).
__device__ __forceinline__ int swz(int R, int lk) {
    return R * 32 + ((lk ^ ((R >> 1) & 3)) << 3);
}
// fp8 BK=128 swizzle: slot = g ^ (R&7) ^ (bit3(R)<<2)
__device__ __forceinline__ int mix8(int R) {
    return (R & 7) ^ ((R >> 1) & 4);
}

// ---------------------------------------------------------------------------
// Fused convert: h_i,h_j -> fp8 Hq; W1 -> fp8*32 W1q; W2 -> bf16 W2b.
// ---------------------------------------------------------------------------
#define G1 1048576   // h_i float4-groups
#define G2 2097152
#define G3 3145728
#define G4 3276800
__global__ __launch_bounds__(256) void cvt_all_kernel(
    const float* __restrict__ h_i, const float* __restrict__ h_j,
    const float* __restrict__ W1,  const float* __restrict__ W2,
    unsigned char* __restrict__ Hq, unsigned char* __restrict__ W1q,
    unsigned short* __restrict__ W2b)
{
    int i = blockIdx.x * 256 + threadIdx.x;
    if (i >= G4) return;
    if (i < G2) {
        const float* src = (i < G1) ? h_i : h_j;
        int off = (i < G1) ? i : i - G1;
        float4 v = reinterpret_cast<const float4*>(src)[off];
        uchar4 o;
        o.x = f2fp8(v.x); o.y = f2fp8(v.y); o.z = f2fp8(v.z); o.w = f2fp8(v.w);
        reinterpret_cast<uchar4*>(Hq)[i] = o;
    } else if (i < G3) {
        int off = i - G2;
        float4 v = reinterpret_cast<const float4*>(W1)[off];
        uchar4 o;
        o.x = f2fp8(v.x * W1SCALE); o.y = f2fp8(v.y * W1SCALE);
        o.z = f2fp8(v.z * W1SCALE); o.w = f2fp8(v.w * W1SCALE);
        reinterpret_cast<uchar4*>(W1q)[off] = o;
    } else {
        int off = i - G3;
        float4 v = reinterpret_cast<const float4*>(W2)[off];
        ushort4 o;
        o.x = f2bf(v.x); o.y = f2bf(v.y); o.z = f2bf(v.z); o.w = f2bf(v.w);
        reinterpret_cast<ushort4*>(W2b)[off] = o;
    }
}

// ---------------------------------------------------------------------------
// bf16 single-buffer MFMA K-loop (R5 structure). BM=WM*32, BN=WN*32, BK=32.
// ---------------------------------------------------------------------------
template<int KSTRIDE, int KLEN, int WM, int WN>
__device__ __forceinline__ void mfma_loop(
    const unsigned short* __restrict__ Ab,
    const unsigned short* __restrict__ Bb,
    unsigned short* As, unsigned short* Bs,
    f32x4 acc[WM][WN], int tid)
{
    constexpr int BM = WM * 32;
    constexpr int BN = WN * 32;
    const int wid = tid >> 6, lane = tid & 63;
    const int mblk = (wid >> 1) * (WM * 16);
    const int nblk = (wid & 1) * (WN * 16);
    const int lr = lane & 15, lk = lane >> 4;
    for (int k0 = 0; k0 < KLEN; k0 += 32) {
        __syncthreads();
        #pragma unroll
        for (int u = 0; u < BM / 64; ++u) {
            int li = u * 256 + tid;
            int r = li >> 2, c = (li & 3) ^ ((li >> 3) & 3);
            gl_lds16(Ab + (size_t)r * KSTRIDE + k0 + c * 8, As + li * 8);
        }
        #pragma unroll
        for (int u = 0; u < BN / 64; ++u) {
            int li = u * 256 + tid;
            int r = li >> 2, c = (li & 3) ^ ((li >> 3) & 3);
            gl_lds16(Bb + (size_t)r * KSTRIDE + k0 + c * 8, Bs + li * 8);
        }
        __syncthreads();
        bf16x8 af[WM], bv[WN];
        #pragma unroll
        for (int i = 0; i < WM; ++i)
            af[i] = *reinterpret_cast<const bf16x8*>(As + swz(mblk + i * 16 + lr, lk));
        #pragma unroll
        for (int j = 0; j < WN; ++j)
            bv[j] = *reinterpret_cast<const bf16x8*>(Bs + swz(nblk + j * 16 + lr, lk));
        #pragma unroll
        for (int i = 0; i < WM; ++i)
            #pragma unroll
            for (int j = 0; j < WN; ++j)
                acc[i][j] = __builtin_amdgcn_mfma_f32_16x16x32_bf16(af[i], bv[j], acc[i][j], 0, 0, 0);
    }
}

// ---------------------------------------------------------------------------
// GEMM1 (fp8 e4m3): X[m][n] = sum_k H[m][k]*W1[n][k]  (4096x2048x2048)
// BM=BN=128, BK=128 (16 iters). LDS 2x16KB. W1 pre-scaled x32 -> acc * 1/32.
// Epilogue: bf16 X store + fused BN column stats.
// ---------------------------------------------------------------------------
__global__ __launch_bounds__(256) void gemm1_fp8(
    const unsigned char* __restrict__ Hq, const unsigned char* __restrict__ W1q,
    unsigned short* __restrict__ Xb, float* __restrict__ sums, float* __restrict__ sumsqs)
{
    __shared__ __align__(16) unsigned char As[128 * 128];
    __shared__ __align__(16) unsigned char Bs[128 * 128];
    const int tid = threadIdx.x;
    const int m0 = blockIdx.y * 128, n0 = blockIdx.x * 128;
    const unsigned char* Ab = Hq + (size_t)m0 * LATENT;
    const unsigned char* Bb = W1q + (size_t)n0 * LATENT;
    const int wid = tid >> 6, lane = tid & 63;
    const int mblk = (wid >> 1) * 64, nblk = (wid & 1) * 64;
    const int lr = lane & 15, lk = lane >> 4;
    f32x4 zero = {0.f, 0.f, 0.f, 0.f};
    f32x4 acc[4][4];
    #pragma unroll
    for (int i = 0; i < 4; ++i)
        #pragma unroll
        for (int j = 0; j < 4; ++j) acc[i][j] = zero;

    for (int k0 = 0; k0 < LATENT; k0 += 128) {
        __syncthreads();
        #pragma unroll
        for (int u = 0; u < 4; ++u) {
            int li = u * 256 + tid;
            int r = li >> 3, s = li & 7;
            int c = s ^ mix8(r);
            gl_lds16(Ab + (size_t)r * LATENT + k0 + c * 16, As + li * 16);
        }
        #pragma unroll
        for (int u = 0; u < 4; ++u) {
            int li = u * 256 + tid;
            int r = li >> 3, s = li & 7;
            int c = s ^ mix8(r);
            gl_lds16(Bb + (size_t)r * LATENT + k0 + c * 16, Bs + li * 16);
        }
        __syncthreads();
        i64 af[4][4], bv[4][4];
        #pragma unroll
        for (int i = 0; i < 4; ++i) {
            int R = mblk + i * 16 + lr;
            int mr = mix8(R);
            int base = R * 128 + (lk & 1) * 8;
            #pragma unroll
            for (int t = 0; t < 4; ++t) {
                int g = 2 * t + (lk >> 1);
                af[i][t] = *reinterpret_cast<const i64*>(As + base + ((g ^ mr) << 4));
            }
        }
        #pragma unroll
        for (int j = 0; j < 4; ++j) {
            int R = nblk + j * 16 + lr;
            int mr = mix8(R);
            int base = R * 128 + (lk & 1) * 8;
            #pragma unroll
            for (int t = 0; t < 4; ++t) {
                int g = 2 * t + (lk >> 1);
                bv[j][t] = *reinterpret_cast<const i64*>(Bs + base + ((g ^ mr) << 4));
            }
        }
        #pragma unroll
        for (int t = 0; t < 4; ++t)
            #pragma unroll
            for (int i = 0; i < 4; ++i)
                #pragma unroll
                for (int j = 0; j < 4; ++j)
                    acc[i][j] = __builtin_amdgcn_mfma_f32_16x16x32_fp8_fp8(
                        af[i][t], bv[j][t], acc[i][j], 0, 0, 0);
    }

    const int lq = lane >> 4;
    const int half = m0 >> 11;
    #pragma unroll
    for (int j = 0; j < 4; ++j) {
        float s = 0.f, q = 0.f;
        #pragma unroll
        for (int i = 0; i < 4; ++i)
            #pragma unroll
            for (int r = 0; r < 4; ++r) {
                float v = acc[i][j][r] * W1INV;
                s += v; q += v * v;
                int row = m0 + mblk + i * 16 + lq * 4 + r;
                int col = n0 + nblk + j * 16 + lr;
                Xb[(size_t)row * LATENT + col] = f2bf(v);
            }
        s += __shfl_xor(s, 16, 64);  q += __shfl_xor(q, 16, 64);
        s += __shfl_xor(s, 32, 64);  q += __shfl_xor(q, 32, 64);
        if (lq == 0) {
            int col = n0 + nblk + j * 16 + lr;
            atomicAdd(&sums[half * LATENT + col], s);
            atomicAdd(&sumsqs[half * LATENT + col], q);
        }
    }
}

// ---------------------------------------------------------------------------
// BN finalize: per (half, col) scale/shift.
// ---------------------------------------------------------------------------
__global__ __launch_bounds__(256) void bn_final_kernel(
    const float* __restrict__ sums, const float* __restrict__ sumsqs,
    const float* __restrict__ gamma, const float* __restrict__ beta,
    float* __restrict__ scaleA, float* __restrict__ shiftA)
{
    const int idx = blockIdx.x * 256 + threadIdx.x;   // 0..4095
    const int c = idx & (LATENT - 1);
    float mu  = sums[idx] * (1.0f / BATCH);
    float var = sumsqs[idx] * (1.0f / BATCH) - mu * mu;
    float inv = rsqrtf(var + BN_EPS);
    float sc = gamma[c] * inv;
    scaleA[idx] = sc;
    shiftA[idx] = beta[c] - mu * sc;
}

// ---------------------------------------------------------------------------
// GEMM2 split-K=4 with fused BN+ReLU on A-fragments:
// Zp[kc][m][n] = sum_{k in chunk} relu(X[m][k]*sc[k]+sh[k]) * W2[n][k]
// BM=128 x BN=64 x KC=512 -> 512 blocks.
// ---------------------------------------------------------------------------
__global__ __launch_bounds__(256) void gemm2_mfma(
    const unsigned short* __restrict__ Xb, const unsigned short* __restrict__ W2b,
    const float* __restrict__ scaleA, const float* __restrict__ shiftA,
    float* __restrict__ Zp)
{
    __shared__ __align__(16) unsigned short As[128 * 32];
    __shared__ __align__(16) unsigned short Bs[64 * 32];
    const int tid = threadIdx.x;
    const int m0 = blockIdx.y * 128, n0 = blockIdx.x * 64, kc = blockIdx.z;
    const unsigned short* Ab = Xb + (size_t)m0 * LATENT + kc * 512;
    const unsigned short* Bb = W2b + (size_t)n0 * LATENT + kc * 512;
    const int half = m0 >> 11;
    const float* scp = scaleA + half * LATENT + kc * 512;
    const float* shp = shiftA + half * LATENT + kc * 512;
    const int wid = tid >> 6, lane = tid & 63;
    const int mblk = (wid >> 1) * 64, nblk = (wid & 1) * 32;
    const int lr = lane & 15, lk = lane >> 4;
    f32x4 zero = {0.f, 0.f, 0.f, 0.f};
    f32x4 acc[4][2];
    #pragma unroll
    for (int i = 0; i < 4; ++i) { acc[i][0] = zero; acc[i][1] = zero; }

    for (int k0 = 0; k0 < 512; k0 += 32) {
        __syncthreads();
        #pragma unroll
        for (int u = 0; u < 2; ++u) {
            int li = u * 256 + tid;
            int r = li >> 2, c = (li & 3) ^ ((li >> 3) & 3);
            gl_lds16(Ab + (size_t)r * LATENT + k0 + c * 8, As + li * 8);
        }
        {
            int li = tid;
            int r = li >> 2, c = (li & 3) ^ ((li >> 3) & 3);
            gl_lds16(Bb + (size_t)r * LATENT + k0 + c * 8, Bs + li * 8);
        }
        __syncthreads();
        // BN params for this lane's k-range (k0 + lk*8 .. +8)
        float4 sc0 = *reinterpret_cast<const float4*>(scp + k0 + lk * 8);
        float4 sc1 = *reinterpret_cast<const float4*>(scp + k0 + lk * 8 + 4);
        float4 sh0 = *reinterpret_cast<const float4*>(shp + k0 + lk * 8);
        float4 sh1 = *reinterpret_cast<const float4*>(shp + k0 + lk * 8 + 4);
        bf16x8 af[4], bv[2];
        #pragma unroll
        for (int i = 0; i < 4; ++i) {
            bf16x8 raw = *reinterpret_cast<const bf16x8*>(As + swz(mblk + i * 16 + lr, lk));
            bf16x8 a;
            a[0] = (__bf16)fmaxf(fmaf((float)raw[0], sc0.x, sh0.x), 0.f);
            a[1] = (__bf16)fmaxf(fmaf((float)raw[1], sc0.y, sh0.y), 0.f);
            a[2] = (__bf16)fmaxf(fmaf((float)raw[2], sc0.z, sh0.z), 0.f);
            a[3] = (__bf16)fmaxf(fmaf((float)raw[3], sc0.w, sh0.w), 0.f);
            a[4] = (__bf16)fmaxf(fmaf((float)raw[4], sc1.x, sh1.x), 0.f);
            a[5] = (__bf16)fmaxf(fmaf((float)raw[5], sc1.y, sh1.y), 0.f);
            a[6] = (__bf16)fmaxf(fmaf((float)raw[6], sc1.z, sh1.z), 0.f);
            a[7] = (__bf16)fmaxf(fmaf((float)raw[7], sc1.w, sh1.w), 0.f);
            af[i] = a;
        }
        #pragma unroll
        for (int j = 0; j < 2; ++j)
            bv[j] = *reinterpret_cast<const bf16x8*>(Bs + swz(nblk + j * 16 + lr, lk));
        #pragma unroll
        for (int i = 0; i < 4; ++i)
            #pragma unroll
            for (int j = 0; j < 2; ++j)
                acc[i][j] = __builtin_amdgcn_mfma_f32_16x16x32_bf16(af[i], bv[j], acc[i][j], 0, 0, 0);
    }

    float* Zk = Zp + (size_t)kc * NROWS * PROJ;
    const int lq = lane >> 4;
    #pragma unroll
    for (int i = 0; i < 4; ++i)
        #pragma unroll
        for (int j = 0; j < 2; ++j)
            #pragma unroll
            for (int r = 0; r < 4; ++r) {
                int row = m0 + mblk + i * 16 + lq * 4 + r;
                int col = n0 + nblk + j * 16 + lr;
                Zk[(size_t)row * PROJ + col] = acc[i][j][r];
            }
}

// ---------------------------------------------------------------------------
// Sum 4 K-partials + b2, L2-normalize row -> bf16 ZNb. One wave per row.
// ---------------------------------------------------------------------------
__global__ __launch_bounds__(256) void rownorm_kernel(
    const float* __restrict__ Zp, const float* __restrict__ b2,
    unsigned short* __restrict__ ZNb)
{
    const int wave = threadIdx.x >> 6;
    const int lane = threadIdx.x & 63;
    const int row = blockIdx.x * 4 + wave;
    float v[4];
    float sq = 0.f;
    #pragma unroll
    for (int i = 0; i < 4; ++i) {
        int col = lane + i * 64;
        float t = b2[col];
        #pragma unroll
        for (int c = 0; c < 4; ++c)
            t += Zp[(size_t)c * NROWS * PROJ + (size_t)row * PROJ + col];
        v[i] = t;
        sq += t * t;
    }
    #pragma unroll
    for (int off = 32; off > 0; off >>= 1) sq += __shfl_xor(sq, off, 64);
    float inv = 1.0f / fmaxf(sqrtf(sq), COS_EPS);
    #pragma unroll
    for (int i = 0; i < 4; ++i)
        ZNb[(size_t)row * PROJ + lane + i * 64] = f2bf(v[i] * inv);
}

// ---------------------------------------------------------------------------
// sim tile via MFMA + fused exp/rowsum/diag/pos. K=PROJ=256.
// ---------------------------------------------------------------------------
__global__ __launch_bounds__(256) void simlse_mfma(
    const unsigned short* __restrict__ ZNb, float* __restrict__ rowsum,
    float* __restrict__ dgA, float* __restrict__ posA)
{
    __shared__ __align__(16) unsigned short As[128 * 32];
    __shared__ __align__(16) unsigned short Bs[128 * 32];
    const int tid = threadIdx.x;
    const int r0 = blockIdx.y * 128, j0 = blockIdx.x * 128;
    f32x4 zero = {0.f, 0.f, 0.f, 0.f};
    f32x4 acc[4][4];
    #pragma unroll
    for (int i = 0; i < 4; ++i)
        #pragma unroll
        for (int j = 0; j < 4; ++j) acc[i][j] = zero;
    mfma_loop<PROJ, PROJ, 4, 4>(ZNb + (size_t)r0 * PROJ, ZNb + (size_t)j0 * PROJ,
                                As, Bs, acc, tid);
    const int wid = tid >> 6, lane = tid & 63;
    const int mblk = (wid >> 1) * 64, nblk = (wid & 1) * 64;
    const int lr = lane & 15, lq = lane >> 4;
    #pragma unroll
    for (int i = 0; i < 4; ++i)
        #pragma unroll
        for (int r = 0; r < 4; ++r) {
            int R = r0 + mblk + i * 16 + lq * 4 + r;
            int P = (R < BATCH) ? R + BATCH : R - BATCH;
            float t = 0.f;
            #pragma unroll
            for (int j = 0; j < 4; ++j) {
                int J = j0 + nblk + j * 16 + lr;
                float s = acc[i][j][r] * TEMP_INV;
                float e = __expf(s);
                t += e;
                if (J == R) dgA[R] = e;     // unique writer
                if (J == P) posA[R] = s;    // unique writer
            }
            t += __shfl_xor(t, 1, 64);
            t += __shfl_xor(t, 2, 64);
            t += __shfl_xor(t, 4, 64);
            t += __shfl_xor(t, 8, 64);
            if (lr == 0) atomicAdd(&rowsum[R], t);
        }
}

// loss = (1/N) * sum_r [ log(rowsum_r - diag_r) - pos_r ]
__global__ __launch_bounds__(256) void loss_kernel(
    const float* __restrict__ rowsum, const float* __restrict__ dgA,
    const float* __restrict__ posA, float* __restrict__ out)
{
    __shared__ float red[256];
    float s = 0.f;
    for (int r = threadIdx.x; r < NROWS; r += 256)
        s += logf(rowsum[r] - dgA[r]) - posA[r];
    red[threadIdx.x] = s;
    __syncthreads();
    for (int off = 128; off > 0; off >>= 1) {
        if (threadIdx.x < off) red[threadIdx.x] += red[threadIdx.x + off];
        __syncthreads();
    }
    if (threadIdx.x == 0) out[0] = red[0] * (1.0f / NROWS);
}

// ---------------------------------------------------------------------------
extern "C" void kernel_launch(void* const* d_in, const int* in_sizes, int n_in,
                              void* d_out, int out_size, void* d_ws, size_t ws_size,
                              hipStream_t stream)
{
    const float* h_i   = (const float*)d_in[0];
    const float* h_j   = (const float*)d_in[1];
    const float* W1    = (const float*)d_in[2];
    const float* gamma = (const float*)d_in[3];
    const float* beta  = (const float*)d_in[4];
    const float* W2    = (const float*)d_in[5];
    const float* b2    = (const float*)d_in[6];
    float* out = (float*)d_out;

    // workspace (~48 MB)
    float* Zp     = (float*)d_ws;                        // 4 * 4096*256 fp32
    float* sums   = Zp + (size_t)4 * NROWS * PROJ;       // 4096
    float* sumsqs = sums + 2 * LATENT;                   // 4096
    float* rowsum = sumsqs + 2 * LATENT;                 // 4096
    float* scaleA = rowsum + NROWS;                      // 4096
    float* shiftA = scaleA + 2 * LATENT;                 // 4096
    float* dgA    = shiftA + 2 * LATENT;                 // 4096
    float* posA   = dgA + NROWS;                         // 4096
    unsigned char* Hq  = (unsigned char*)(posA + NROWS);     // 4096*2048 fp8
    unsigned char* W1q = Hq + (size_t)NROWS * LATENT;        // 2048*2048 fp8
    unsigned short* W2b = (unsigned short*)(W1q + (size_t)LATENT * LATENT); // 256*2048 bf16
    unsigned short* Xb  = W2b + (size_t)PROJ * LATENT;       // 4096*2048 bf16
    unsigned short* ZNb = Xb + (size_t)NROWS * LATENT;       // 4096*256 bf16

    // zero atomic accumulators (sums, sumsqs, rowsum contiguous = 12288 floats)
    hipMemsetAsync(sums, 0, (size_t)(4 * LATENT + NROWS) * sizeof(float), stream);

    cvt_all_kernel<<<(G4 + 255) / 256, 256, 0, stream>>>(h_i, h_j, W1, W2, Hq, W1q, W2b);
    gemm1_fp8<<<dim3(LATENT / 128, NROWS / 128), 256, 0, stream>>>(Hq, W1q, Xb, sums, sumsqs);
    bn_final_kernel<<<(2 * LATENT) / 256, 256, 0, stream>>>(sums, sumsqs, gamma, beta, scaleA, shiftA);
    gemm2_mfma<<<dim3(PROJ / 64, NROWS / 128, 4), 256, 0, stream>>>(Xb, W2b, scaleA, shiftA, Zp);
    rownorm_kernel<<<NROWS / 4, 256, 0, stream>>>(Zp, b2, ZNb);
    simlse_mfma<<<dim3(NROWS / 128, NROWS / 128), 256, 0, stream>>>(ZNb, rowsum, dgA, posA);
    loss_kernel<<<1, 256, 0, stream>>>(rowsum, dgA, posA, out);
}

// Round 8
// 185.429 us; speedup vs baseline: 1.1554x; 1.0300x over previous
//
#include <hip/hip_runtime.h>
#include <hip/hip_fp8.h>
#include <math.h>

#define BATCH   2048
#define NROWS   4096   // 2*BATCH
#define LATENT  2048
#define PROJ    256
#define TEMP_INV 2.0f      // 1/0.5
#define BN_EPS  1e-5f
#define COS_EPS 1e-8f
#define W1SCALE 32.0f      // W1 pre-scaled into e4m3 normal range
#define W1INV   (1.0f / 32.0f)

typedef __bf16 bf16x8 __attribute__((ext_vector_type(8)));
typedef float  f32x4  __attribute__((ext_vector_type(4)));
typedef long   i64;

__device__ __forceinline__ unsigned short f2bf(float f) {
    union { float f; unsigned int u; } c; c.f = f;
    return (unsigned short)((c.u + 0x7FFFu + ((c.u >> 16) & 1u)) >> 16);
}
__device__ __forceinline__ float bf2f(unsigned short h) {
    union { unsigned int u; float f; } c; c.u = ((unsigned int)h) << 16;
    return c.f;
}
__device__ __forceinline__ unsigned char f2fp8(float f) {
    __hip_fp8_e4m3 t(f);
    return (unsigned char)t.__x;
}

// async global->LDS, 16 bytes per lane. LDS dest is wave-uniform base + lane*16.
__device__ __forceinline__ void gl_lds16(const void* g, void* l) {
    __builtin_amdgcn_global_load_lds(
        (const __attribute__((address_space(1))) void*)g,
        (__attribute__((address_space(3))) void*)l, 16, 0, 0);
}

// bf16 LDS element offset of (row R, k-chunk lk); granule (R,c) at slot c^((R>>1)&3).
__device__ __forceinline__ int swz(int R, int lk) {
    return R * 32 + ((lk ^ ((R >> 1) & 3)) << 3);
}
// fp8 BK=128 swizzle: slot = g ^ (R&7) ^ (bit3(R)<<2)
__device__ __forceinline__ int mix8(int R) {
    return (R & 7) ^ ((R >> 1) & 4);
}

// ---------------------------------------------------------------------------
// Fused convert: h_i,h_j -> fp8 Hq; W1 -> fp8*32 W1q; W2 -> bf16 W2b.
// ---------------------------------------------------------------------------
#define G1 1048576   // h_i float4-groups
#define G2 2097152
#define G3 3145728
#define G4 3276800
__global__ __launch_bounds__(256) void cvt_all_kernel(
    const float* __restrict__ h_i, const float* __restrict__ h_j,
    const float* __restrict__ W1,  const float* __restrict__ W2,
    unsigned char* __restrict__ Hq, unsigned char* __restrict__ W1q,
    unsigned short* __restrict__ W2b)
{
    int i = blockIdx.x * 256 + threadIdx.x;
    if (i >= G4) return;
    if (i < G2) {
        const float* src = (i < G1) ? h_i : h_j;
        int off = (i < G1) ? i : i - G1;
        float4 v = reinterpret_cast<const float4*>(src)[off];
        uchar4 o;
        o.x = f2fp8(v.x); o.y = f2fp8(v.y); o.z = f2fp8(v.z); o.w = f2fp8(v.w);
        reinterpret_cast<uchar4*>(Hq)[i] = o;
    } else if (i < G3) {
        int off = i - G2;
        float4 v = reinterpret_cast<const float4*>(W1)[off];
        uchar4 o;
        o.x = f2fp8(v.x * W1SCALE); o.y = f2fp8(v.y * W1SCALE);
        o.z = f2fp8(v.z * W1SCALE); o.w = f2fp8(v.w * W1SCALE);
        reinterpret_cast<uchar4*>(W1q)[off] = o;
    } else {
        int off = i - G3;
        float4 v = reinterpret_cast<const float4*>(W2)[off];
        ushort4 o;
        o.x = f2bf(v.x); o.y = f2bf(v.y); o.z = f2bf(v.z); o.w = f2bf(v.w);
        reinterpret_cast<ushort4*>(W2b)[off] = o;
    }
}

// ---------------------------------------------------------------------------
// bf16 single-buffer MFMA K-loop (R5 structure). BM=WM*32, BN=WN*32, BK=32.
// ---------------------------------------------------------------------------
template<int KSTRIDE, int KLEN, int WM, int WN>
__device__ __forceinline__ void mfma_loop(
    const unsigned short* __restrict__ Ab,
    const unsigned short* __restrict__ Bb,
    unsigned short* As, unsigned short* Bs,
    f32x4 acc[WM][WN], int tid)
{
    constexpr int BM = WM * 32;
    constexpr int BN = WN * 32;
    const int wid = tid >> 6, lane = tid & 63;
    const int mblk = (wid >> 1) * (WM * 16);
    const int nblk = (wid & 1) * (WN * 16);
    const int lr = lane & 15, lk = lane >> 4;
    for (int k0 = 0; k0 < KLEN; k0 += 32) {
        __syncthreads();
        #pragma unroll
        for (int u = 0; u < BM / 64; ++u) {
            int li = u * 256 + tid;
            int r = li >> 2, c = (li & 3) ^ ((li >> 3) & 3);
            gl_lds16(Ab + (size_t)r * KSTRIDE + k0 + c * 8, As + li * 8);
        }
        #pragma unroll
        for (int u = 0; u < BN / 64; ++u) {
            int li = u * 256 + tid;
            int r = li >> 2, c = (li & 3) ^ ((li >> 3) & 3);
            gl_lds16(Bb + (size_t)r * KSTRIDE + k0 + c * 8, Bs + li * 8);
        }
        __syncthreads();
        bf16x8 af[WM], bv[WN];
        #pragma unroll
        for (int i = 0; i < WM; ++i)
            af[i] = *reinterpret_cast<const bf16x8*>(As + swz(mblk + i * 16 + lr, lk));
        #pragma unroll
        for (int j = 0; j < WN; ++j)
            bv[j] = *reinterpret_cast<const bf16x8*>(Bs + swz(nblk + j * 16 + lr, lk));
        #pragma unroll
        for (int i = 0; i < WM; ++i)
            #pragma unroll
            for (int j = 0; j < WN; ++j)
                acc[i][j] = __builtin_amdgcn_mfma_f32_16x16x32_bf16(af[i], bv[j], acc[i][j], 0, 0, 0);
    }
}

// ---------------------------------------------------------------------------
// GEMM1 (fp8 e4m3): X[m][n] = sum_k H[m][k]*W1[n][k]  (4096x2048x2048)
// BM=BN=128, BK=128 (16 iters). LDS 2x16KB. W1 pre-scaled x32 -> acc * 1/32.
// Epilogue: bf16 X store + fused BN column stats.
// ---------------------------------------------------------------------------
__global__ __launch_bounds__(256) void gemm1_fp8(
    const unsigned char* __restrict__ Hq, const unsigned char* __restrict__ W1q,
    unsigned short* __restrict__ Xb, float* __restrict__ sums, float* __restrict__ sumsqs)
{
    __shared__ __align__(16) unsigned char As[128 * 128];
    __shared__ __align__(16) unsigned char Bs[128 * 128];
    const int tid = threadIdx.x;
    const int m0 = blockIdx.y * 128, n0 = blockIdx.x * 128;
    const unsigned char* Ab = Hq + (size_t)m0 * LATENT;
    const unsigned char* Bb = W1q + (size_t)n0 * LATENT;
    const int wid = tid >> 6, lane = tid & 63;
    const int mblk = (wid >> 1) * 64, nblk = (wid & 1) * 64;
    const int lr = lane & 15, lk = lane >> 4;
    f32x4 zero = {0.f, 0.f, 0.f, 0.f};
    f32x4 acc[4][4];
    #pragma unroll
    for (int i = 0; i < 4; ++i)
        #pragma unroll
        for (int j = 0; j < 4; ++j) acc[i][j] = zero;

    for (int k0 = 0; k0 < LATENT; k0 += 128) {
        __syncthreads();
        #pragma unroll
        for (int u = 0; u < 4; ++u) {
            int li = u * 256 + tid;
            int r = li >> 3, s = li & 7;
            int c = s ^ mix8(r);
            gl_lds16(Ab + (size_t)r * LATENT + k0 + c * 16, As + li * 16);
        }
        #pragma unroll
        for (int u = 0; u < 4; ++u) {
            int li = u * 256 + tid;
            int r = li >> 3, s = li & 7;
            int c = s ^ mix8(r);
            gl_lds16(Bb + (size_t)r * LATENT + k0 + c * 16, Bs + li * 16);
        }
        __syncthreads();
        i64 af[4][4], bv[4][4];
        #pragma unroll
        for (int i = 0; i < 4; ++i) {
            int R = mblk + i * 16 + lr;
            int mr = mix8(R);
            int base = R * 128 + (lk & 1) * 8;
            #pragma unroll
            for (int t = 0; t < 4; ++t) {
                int g = 2 * t + (lk >> 1);
                af[i][t] = *reinterpret_cast<const i64*>(As + base + ((g ^ mr) << 4));
            }
        }
        #pragma unroll
        for (int j = 0; j < 4; ++j) {
            int R = nblk + j * 16 + lr;
            int mr = mix8(R);
            int base = R * 128 + (lk & 1) * 8;
            #pragma unroll
            for (int t = 0; t < 4; ++t) {
                int g = 2 * t + (lk >> 1);
                bv[j][t] = *reinterpret_cast<const i64*>(Bs + base + ((g ^ mr) << 4));
            }
        }
        #pragma unroll
        for (int t = 0; t < 4; ++t)
            #pragma unroll
            for (int i = 0; i < 4; ++i)
                #pragma unroll
                for (int j = 0; j < 4; ++j)
                    acc[i][j] = __builtin_amdgcn_mfma_f32_16x16x32_fp8_fp8(
                        af[i][t], bv[j][t], acc[i][j], 0, 0, 0);
    }

    const int lq = lane >> 4;
    const int half = m0 >> 11;
    #pragma unroll
    for (int j = 0; j < 4; ++j) {
        float s = 0.f, q = 0.f;
        #pragma unroll
        for (int i = 0; i < 4; ++i)
            #pragma unroll
            for (int r = 0; r < 4; ++r) {
                float v = acc[i][j][r] * W1INV;
                s += v; q += v * v;
                int row = m0 + mblk + i * 16 + lq * 4 + r;
                int col = n0 + nblk + j * 16 + lr;
                Xb[(size_t)row * LATENT + col] = f2bf(v);
            }
        s += __shfl_xor(s, 16, 64);  q += __shfl_xor(q, 16, 64);
        s += __shfl_xor(s, 32, 64);  q += __shfl_xor(q, 32, 64);
        if (lq == 0) {
            int col = n0 + nblk + j * 16 + lr;
            atomicAdd(&sums[half * LATENT + col], s);
            atomicAdd(&sumsqs[half * LATENT + col], q);
        }
    }
}

// ---------------------------------------------------------------------------
// BN finalize: per (half, col) scale/shift.
// ---------------------------------------------------------------------------
__global__ __launch_bounds__(256) void bn_final_kernel(
    const float* __restrict__ sums, const float* __restrict__ sumsqs,
    const float* __restrict__ gamma, const float* __restrict__ beta,
    float* __restrict__ scaleA, float* __restrict__ shiftA)
{
    const int idx = blockIdx.x * 256 + threadIdx.x;   // 0..4095
    const int c = idx & (LATENT - 1);
    float mu  = sums[idx] * (1.0f / BATCH);
    float var = sumsqs[idx] * (1.0f / BATCH) - mu * mu;
    float inv = rsqrtf(var + BN_EPS);
    float sc = gamma[c] * inv;
    scaleA[idx] = sc;
    shiftA[idx] = beta[c] - mu * sc;
}

// ---------------------------------------------------------------------------
// GEMM2 split-K=4 with fused BN+ReLU on A-fragments:
// Zp[kc][m][n] = sum_{k in chunk} relu(X[m][k]*sc[k]+sh[k]) * W2[n][k]
// BM=128 x BN=64 x KC=512 -> 512 blocks.
// ---------------------------------------------------------------------------
__global__ __launch_bounds__(256) void gemm2_mfma(
    const unsigned short* __restrict__ Xb, const unsigned short* __restrict__ W2b,
    const float* __restrict__ scaleA, const float* __restrict__ shiftA,
    float* __restrict__ Zp)
{
    __shared__ __align__(16) unsigned short As[128 * 32];
    __shared__ __align__(16) unsigned short Bs[64 * 32];
    const int tid = threadIdx.x;
    const int m0 = blockIdx.y * 128, n0 = blockIdx.x * 64, kc = blockIdx.z;
    const unsigned short* Ab = Xb + (size_t)m0 * LATENT + kc * 512;
    const unsigned short* Bb = W2b + (size_t)n0 * LATENT + kc * 512;
    const int half = m0 >> 11;
    const float* scp = scaleA + half * LATENT + kc * 512;
    const float* shp = shiftA + half * LATENT + kc * 512;
    const int wid = tid >> 6, lane = tid & 63;
    const int mblk = (wid >> 1) * 64, nblk = (wid & 1) * 32;
    const int lr = lane & 15, lk = lane >> 4;
    f32x4 zero = {0.f, 0.f, 0.f, 0.f};
    f32x4 acc[4][2];
    #pragma unroll
    for (int i = 0; i < 4; ++i) { acc[i][0] = zero; acc[i][1] = zero; }

    for (int k0 = 0; k0 < 512; k0 += 32) {
        __syncthreads();
        #pragma unroll
        for (int u = 0; u < 2; ++u) {
            int li = u * 256 + tid;
            int r = li >> 2, c = (li & 3) ^ ((li >> 3) & 3);
            gl_lds16(Ab + (size_t)r * LATENT + k0 + c * 8, As + li * 8);
        }
        {
            int li = tid;
            int r = li >> 2, c = (li & 3) ^ ((li >> 3) & 3);
            gl_lds16(Bb + (size_t)r * LATENT + k0 + c * 8, Bs + li * 8);
        }
        __syncthreads();
        // BN params for this lane's k-range (k0 + lk*8 .. +8)
        float4 sc0 = *reinterpret_cast<const float4*>(scp + k0 + lk * 8);
        float4 sc1 = *reinterpret_cast<const float4*>(scp + k0 + lk * 8 + 4);
        float4 sh0 = *reinterpret_cast<const float4*>(shp + k0 + lk * 8);
        float4 sh1 = *reinterpret_cast<const float4*>(shp + k0 + lk * 8 + 4);
        bf16x8 af[4], bv[2];
        #pragma unroll
        for (int i = 0; i < 4; ++i) {
            bf16x8 raw = *reinterpret_cast<const bf16x8*>(As + swz(mblk + i * 16 + lr, lk));
            bf16x8 a;
            a[0] = (__bf16)fmaxf(fmaf((float)raw[0], sc0.x, sh0.x), 0.f);
            a[1] = (__bf16)fmaxf(fmaf((float)raw[1], sc0.y, sh0.y), 0.f);
            a[2] = (__bf16)fmaxf(fmaf((float)raw[2], sc0.z, sh0.z), 0.f);
            a[3] = (__bf16)fmaxf(fmaf((float)raw[3], sc0.w, sh0.w), 0.f);
            a[4] = (__bf16)fmaxf(fmaf((float)raw[4], sc1.x, sh1.x), 0.f);
            a[5] = (__bf16)fmaxf(fmaf((float)raw[5], sc1.y, sh1.y), 0.f);
            a[6] = (__bf16)fmaxf(fmaf((float)raw[6], sc1.z, sh1.z), 0.f);
            a[7] = (__bf16)fmaxf(fmaf((float)raw[7], sc1.w, sh1.w), 0.f);
            af[i] = a;
        }
        #pragma unroll
        for (int j = 0; j < 2; ++j)
            bv[j] = *reinterpret_cast<const bf16x8*>(Bs + swz(nblk + j * 16 + lr, lk));
        #pragma unroll
        for (int i = 0; i < 4; ++i)
            #pragma unroll
            for (int j = 0; j < 2; ++j)
                acc[i][j] = __builtin_amdgcn_mfma_f32_16x16x32_bf16(af[i], bv[j], acc[i][j], 0, 0, 0);
    }

    float* Zk = Zp + (size_t)kc * NROWS * PROJ;
    const int lq = lane >> 4;
    #pragma unroll
    for (int i = 0; i < 4; ++i)
        #pragma unroll
        for (int j = 0; j < 2; ++j)
            #pragma unroll
            for (int r = 0; r < 4; ++r) {
                int row = m0 + mblk + i * 16 + lq * 4 + r;
                int col = n0 + nblk + j * 16 + lr;
                Zk[(size_t)row * PROJ + col] = acc[i][j][r];
            }
}

// ---------------------------------------------------------------------------
// Sum 4 K-partials + b2, L2-normalize row -> bf16 ZNb. One wave per row.
// ---------------------------------------------------------------------------
__global__ __launch_bounds__(256) void rownorm_kernel(
    const float* __restrict__ Zp, const float* __restrict__ b2,
    unsigned short* __restrict__ ZNb)
{
    const int wave = threadIdx.x >> 6;
    const int lane = threadIdx.x & 63;
    const int row = blockIdx.x * 4 + wave;
    float v[4];
    float sq = 0.f;
    #pragma unroll
    for (int i = 0; i < 4; ++i) {
        int col = lane + i * 64;
        float t = b2[col];
        #pragma unroll
        for (int c = 0; c < 4; ++c)
            t += Zp[(size_t)c * NROWS * PROJ + (size_t)row * PROJ + col];
        v[i] = t;
        sq += t * t;
    }
    #pragma unroll
    for (int off = 32; off > 0; off >>= 1) sq += __shfl_xor(sq, off, 64);
    float inv = 1.0f / fmaxf(sqrtf(sq), COS_EPS);
    #pragma unroll
    for (int i = 0; i < 4; ++i)
        ZNb[(size_t)row * PROJ + lane + i * 64] = f2bf(v[i] * inv);
}

// ---------------------------------------------------------------------------
// sim tile via MFMA, upper-triangle tiles only (sim is symmetric; MFMA dot
// products are bitwise identical under operand swap). Off-diagonal tiles
// contribute row sums (row reduction) AND column sums (i,r + lq reduction)
// to rowsum. Positive pairs write both posA[R] and posA[pair].
// ---------------------------------------------------------------------------
__global__ __launch_bounds__(256) void simlse_mfma(
    const unsigned short* __restrict__ ZNb, float* __restrict__ rowsum,
    float* __restrict__ dgA, float* __restrict__ posA)
{
    if (blockIdx.x < blockIdx.y) return;   // symmetry: only tj >= ti
    __shared__ __align__(16) unsigned short As[128 * 32];
    __shared__ __align__(16) unsigned short Bs[128 * 32];
    const int tid = threadIdx.x;
    const int r0 = blockIdx.y * 128, j0 = blockIdx.x * 128;
    const bool offdiag = (j0 != r0);
    f32x4 zero = {0.f, 0.f, 0.f, 0.f};
    f32x4 acc[4][4];
    #pragma unroll
    for (int i = 0; i < 4; ++i)
        #pragma unroll
        for (int j = 0; j < 4; ++j) acc[i][j] = zero;
    mfma_loop<PROJ, PROJ, 4, 4>(ZNb + (size_t)r0 * PROJ, ZNb + (size_t)j0 * PROJ,
                                As, Bs, acc, tid);
    const int wid = tid >> 6, lane = tid & 63;
    const int mblk = (wid >> 1) * 64, nblk = (wid & 1) * 64;
    const int lr = lane & 15, lq = lane >> 4;
    float tcol[4] = {0.f, 0.f, 0.f, 0.f};
    #pragma unroll
    for (int i = 0; i < 4; ++i)
        #pragma unroll
        for (int r = 0; r < 4; ++r) {
            int R = r0 + mblk + i * 16 + lq * 4 + r;
            int P = (R < BATCH) ? R + BATCH : R - BATCH;
            float t = 0.f;
            #pragma unroll
            for (int j = 0; j < 4; ++j) {
                int J = j0 + nblk + j * 16 + lr;
                float s = acc[i][j][r] * TEMP_INV;
                float e = __expf(s);
                t += e;
                tcol[j] += e;
                if (J == R) dgA[R] = e;              // diag tiles only
                if (J == P) { posA[R] = s; posA[J] = s; }  // s[R,P]==s[P,R]
            }
            t += __shfl_xor(t, 1, 64);
            t += __shfl_xor(t, 2, 64);
            t += __shfl_xor(t, 4, 64);
            t += __shfl_xor(t, 8, 64);
            if (lr == 0) atomicAdd(&rowsum[R], t);
        }
    if (offdiag) {
        // column sums = the mirror tile's row sums (bitwise-identical terms)
        #pragma unroll
        for (int j = 0; j < 4; ++j) {
            float c = tcol[j];
            c += __shfl_xor(c, 16, 64);
            c += __shfl_xor(c, 32, 64);
            if (lq == 0) atomicAdd(&rowsum[j0 + nblk + j * 16 + lr], c);
        }
    }
}

// loss = (1/N) * sum_r [ log(rowsum_r - diag_r) - pos_r ]
__global__ __launch_bounds__(256) void loss_kernel(
    const float* __restrict__ rowsum, const float* __restrict__ dgA,
    const float* __restrict__ posA, float* __restrict__ out)
{
    __shared__ float red[256];
    float s = 0.f;
    for (int r = threadIdx.x; r < NROWS; r += 256)
        s += logf(rowsum[r] - dgA[r]) - posA[r];
    red[threadIdx.x] = s;
    __syncthreads();
    for (int off = 128; off > 0; off >>= 1) {
        if (threadIdx.x < off) red[threadIdx.x] += red[threadIdx.x + off];
        __syncthreads();
    }
    if (threadIdx.x == 0) out[0] = red[0] * (1.0f / NROWS);
}

// ---------------------------------------------------------------------------
extern "C" void kernel_launch(void* const* d_in, const int* in_sizes, int n_in,
                              void* d_out, int out_size, void* d_ws, size_t ws_size,
                              hipStream_t stream)
{
    const float* h_i   = (const float*)d_in[0];
    const float* h_j   = (const float*)d_in[1];
    const float* W1    = (const float*)d_in[2];
    const float* gamma = (const float*)d_in[3];
    const float* beta  = (const float*)d_in[4];
    const float* W2    = (const float*)d_in[5];
    const float* b2    = (const float*)d_in[6];
    float* out = (float*)d_out;

    // workspace (~48 MB)
    float* Zp     = (float*)d_ws;                        // 4 * 4096*256 fp32
    float* sums   = Zp + (size_t)4 * NROWS * PROJ;       // 4096
    float* sumsqs = sums + 2 * LATENT;                   // 4096
    float* rowsum = sumsqs + 2 * LATENT;                 // 4096
    float* scaleA = rowsum + NROWS;                      // 4096
    float* shiftA = scaleA + 2 * LATENT;                 // 4096
    float* dgA    = shiftA + 2 * LATENT;                 // 4096
    float* posA   = dgA + NROWS;                         // 4096
    unsigned char* Hq  = (unsigned char*)(posA + NROWS);     // 4096*2048 fp8
    unsigned char* W1q = Hq + (size_t)NROWS * LATENT;        // 2048*2048 fp8
    unsigned short* W2b = (unsigned short*)(W1q + (size_t)LATENT * LATENT); // 256*2048 bf16
    unsigned short* Xb  = W2b + (size_t)PROJ * LATENT;       // 4096*2048 bf16
    unsigned short* ZNb = Xb + (size_t)NROWS * LATENT;       // 4096*256 bf16

    // zero atomic accumulators (sums, sumsqs, rowsum contiguous = 12288 floats)
    hipMemsetAsync(sums, 0, (size_t)(4 * LATENT + NROWS) * sizeof(float), stream);

    cvt_all_kernel<<<(G4 + 255) / 256, 256, 0, stream>>>(h_i, h_j, W1, W2, Hq, W1q, W2b);
    gemm1_fp8<<<dim3(LATENT / 128, NROWS / 128), 256, 0, stream>>>(Hq, W1q, Xb, sums, sumsqs);
    bn_final_kernel<<<(2 * LATENT) / 256, 256, 0, stream>>>(sums, sumsqs, gamma, beta, scaleA, shiftA);
    gemm2_mfma<<<dim3(PROJ / 64, NROWS / 128, 4), 256, 0, stream>>>(Xb, W2b, scaleA, shiftA, Zp);
    rownorm_kernel<<<NROWS / 4, 256, 0, stream>>>(Zp, b2, ZNb);
    simlse_mfma<<<dim3(NROWS / 128, NROWS / 128), 256, 0, stream>>>(ZNb, rowsum, dgA, posA);
    loss_kernel<<<1, 256, 0, stream>>>(rowsum, dgA, posA, out);
}

// Round 9
// 176.031 us; speedup vs baseline: 1.2171x; 1.0534x over previous
//
#include <hip/hip_runtime.h>
#include <hip/hip_fp8.h>
#include <math.h>

#define BATCH   2048
#define NROWS   4096   // 2*BATCH
#define LATENT  2048
#define PROJ    256
#define TEMP_INV 2.0f      // 1/0.5
#define BN_EPS  1e-5f
#define COS_EPS 1e-8f
#define W1SCALE 32.0f      // W1 pre-scaled into e4m3 normal range
#define W1INV   (1.0f / 32.0f)

typedef __bf16 bf16x8 __attribute__((ext_vector_type(8)));
typedef float  f32x4  __attribute__((ext_vector_type(4)));
typedef long   i64;

__device__ __forceinline__ unsigned short f2bf(float f) {
    union { float f; unsigned int u; } c; c.f = f;
    return (unsigned short)((c.u + 0x7FFFu + ((c.u >> 16) & 1u)) >> 16);
}
__device__ __forceinline__ float bf2f(unsigned short h) {
    union { unsigned int u; float f; } c; c.u = ((unsigned int)h) << 16;
    return c.f;
}
__device__ __forceinline__ unsigned char f2fp8(float f) {
    __hip_fp8_e4m3 t(f);
    return (unsigned char)t.__x;
}

// async global->LDS, 16 bytes per lane. LDS dest is wave-uniform base + lane*16.
__device__ __forceinline__ void gl_lds16(const void* g, void* l) {
    __builtin_amdgcn_global_load_lds(
        (const __attribute__((address_space(1))) void*)g,
        (__attribute__((address_space(3))) void*)l, 16, 0, 0);
}

// bf16 LDS element offset of (row R, k-chunk lk); granule (R,c) at slot c^((R>>1)&3).
__device__ __forceinline__ int swz(int R, int lk) {
    return R * 32 + ((lk ^ ((R >> 1) & 3)) << 3);
}
// fp8 BK=128 swizzle: slot = g ^ (R&7) ^ (bit3(R)<<2)
__device__ __forceinline__ int mix8(int R) {
    return (R & 7) ^ ((R >> 1) & 4);
}

// ---------------------------------------------------------------------------
// Fused convert: h_i,h_j -> fp8 Hq; W1 -> fp8*32 W1q; W2 -> bf16 W2b.
// ---------------------------------------------------------------------------
#define G1 1048576   // h_i float4-groups
#define G2 2097152
#define G3 3145728
#define G4 3276800
__global__ __launch_bounds__(256) void cvt_all_kernel(
    const float* __restrict__ h_i, const float* __restrict__ h_j,
    const float* __restrict__ W1,  const float* __restrict__ W2,
    unsigned char* __restrict__ Hq, unsigned char* __restrict__ W1q,
    unsigned short* __restrict__ W2b)
{
    int i = blockIdx.x * 256 + threadIdx.x;
    if (i >= G4) return;
    if (i < G2) {
        const float* src = (i < G1) ? h_i : h_j;
        int off = (i < G1) ? i : i - G1;
        float4 v = reinterpret_cast<const float4*>(src)[off];
        uchar4 o;
        o.x = f2fp8(v.x); o.y = f2fp8(v.y); o.z = f2fp8(v.z); o.w = f2fp8(v.w);
        reinterpret_cast<uchar4*>(Hq)[i] = o;
    } else if (i < G3) {
        int off = i - G2;
        float4 v = reinterpret_cast<const float4*>(W1)[off];
        uchar4 o;
        o.x = f2fp8(v.x * W1SCALE); o.y = f2fp8(v.y * W1SCALE);
        o.z = f2fp8(v.z * W1SCALE); o.w = f2fp8(v.w * W1SCALE);
        reinterpret_cast<uchar4*>(W1q)[off] = o;
    } else {
        int off = i - G3;
        float4 v = reinterpret_cast<const float4*>(W2)[off];
        ushort4 o;
        o.x = f2bf(v.x); o.y = f2bf(v.y); o.z = f2bf(v.z); o.w = f2bf(v.w);
        reinterpret_cast<ushort4*>(W2b)[off] = o;
    }
}

// ---------------------------------------------------------------------------
// bf16 single-buffer MFMA K-loop (R5 structure). BM=WM*32, BN=WN*32, BK=32.
// ---------------------------------------------------------------------------
template<int KSTRIDE, int KLEN, int WM, int WN>
__device__ __forceinline__ void mfma_loop(
    const unsigned short* __restrict__ Ab,
    const unsigned short* __restrict__ Bb,
    unsigned short* As, unsigned short* Bs,
    f32x4 acc[WM][WN], int tid)
{
    constexpr int BM = WM * 32;
    constexpr int BN = WN * 32;
    const int wid = tid >> 6, lane = tid & 63;
    const int mblk = (wid >> 1) * (WM * 16);
    const int nblk = (wid & 1) * (WN * 16);
    const int lr = lane & 15, lk = lane >> 4;
    for (int k0 = 0; k0 < KLEN; k0 += 32) {
        __syncthreads();
        #pragma unroll
        for (int u = 0; u < BM / 64; ++u) {
            int li = u * 256 + tid;
            int r = li >> 2, c = (li & 3) ^ ((li >> 3) & 3);
            gl_lds16(Ab + (size_t)r * KSTRIDE + k0 + c * 8, As + li * 8);
        }
        #pragma unroll
        for (int u = 0; u < BN / 64; ++u) {
            int li = u * 256 + tid;
            int r = li >> 2, c = (li & 3) ^ ((li >> 3) & 3);
            gl_lds16(Bb + (size_t)r * KSTRIDE + k0 + c * 8, Bs + li * 8);
        }
        __syncthreads();
        bf16x8 af[WM], bv[WN];
        #pragma unroll
        for (int i = 0; i < WM; ++i)
            af[i] = *reinterpret_cast<const bf16x8*>(As + swz(mblk + i * 16 + lr, lk));
        #pragma unroll
        for (int j = 0; j < WN; ++j)
            bv[j] = *reinterpret_cast<const bf16x8*>(Bs + swz(nblk + j * 16 + lr, lk));
        #pragma unroll
        for (int i = 0; i < WM; ++i)
            #pragma unroll
            for (int j = 0; j < WN; ++j)
                acc[i][j] = __builtin_amdgcn_mfma_f32_16x16x32_bf16(af[i], bv[j], acc[i][j], 0, 0, 0);
    }
}

// ---------------------------------------------------------------------------
// GEMM1 (fp8 e4m3): X[m][n] = sum_k H[m][k]*W1[n][k]  (4096x2048x2048)
// BM=128 x BN=64, BK=128 -> grid (32,32)=1024 blocks = 4/CU (latency hiding).
// LDS 24 KB. W1 pre-scaled x32 -> acc * 1/32.
// Epilogue: bf16 X store + fused BN column stats.
// ---------------------------------------------------------------------------
__global__ __launch_bounds__(256, 4) void gemm1_fp8(
    const unsigned char* __restrict__ Hq, const unsigned char* __restrict__ W1q,
    unsigned short* __restrict__ Xb, float* __restrict__ sums, float* __restrict__ sumsqs)
{
    __shared__ __align__(16) unsigned char As[128 * 128];
    __shared__ __align__(16) unsigned char Bs[64 * 128];
    const int tid = threadIdx.x;
    const int m0 = blockIdx.y * 128, n0 = blockIdx.x * 64;
    const unsigned char* Ab = Hq + (size_t)m0 * LATENT;
    const unsigned char* Bb = W1q + (size_t)n0 * LATENT;
    const int wid = tid >> 6, lane = tid & 63;
    const int mblk = (wid >> 1) * 64, nblk = (wid & 1) * 32;
    const int lr = lane & 15, lk = lane >> 4;
    f32x4 zero = {0.f, 0.f, 0.f, 0.f};
    f32x4 acc[4][2];
    #pragma unroll
    for (int i = 0; i < 4; ++i) { acc[i][0] = zero; acc[i][1] = zero; }

    for (int k0 = 0; k0 < LATENT; k0 += 128) {
        __syncthreads();
        #pragma unroll
        for (int u = 0; u < 4; ++u) {
            int li = u * 256 + tid;
            int r = li >> 3, s = li & 7;
            gl_lds16(Ab + (size_t)r * LATENT + k0 + ((s ^ mix8(r)) * 16), As + li * 16);
        }
        #pragma unroll
        for (int u = 0; u < 2; ++u) {
            int li = u * 256 + tid;
            int r = li >> 3, s = li & 7;
            gl_lds16(Bb + (size_t)r * LATENT + k0 + ((s ^ mix8(r)) * 16), Bs + li * 16);
        }
        __syncthreads();
        i64 af[4][4], bv[2][4];
        #pragma unroll
        for (int i = 0; i < 4; ++i) {
            int R = mblk + i * 16 + lr;
            int mr = mix8(R);
            int base = R * 128 + (lk & 1) * 8;
            #pragma unroll
            for (int t = 0; t < 4; ++t) {
                int g = 2 * t + (lk >> 1);
                af[i][t] = *reinterpret_cast<const i64*>(As + base + ((g ^ mr) << 4));
            }
        }
        #pragma unroll
        for (int j = 0; j < 2; ++j) {
            int R = nblk + j * 16 + lr;
            int mr = mix8(R);
            int base = R * 128 + (lk & 1) * 8;
            #pragma unroll
            for (int t = 0; t < 4; ++t) {
                int g = 2 * t + (lk >> 1);
                bv[j][t] = *reinterpret_cast<const i64*>(Bs + base + ((g ^ mr) << 4));
            }
        }
        #pragma unroll
        for (int t = 0; t < 4; ++t)
            #pragma unroll
            for (int i = 0; i < 4; ++i)
                #pragma unroll
                for (int j = 0; j < 2; ++j)
                    acc[i][j] = __builtin_amdgcn_mfma_f32_16x16x32_fp8_fp8(
                        af[i][t], bv[j][t], acc[i][j], 0, 0, 0);
    }

    const int lq = lane >> 4;
    const int half = m0 >> 11;
    #pragma unroll
    for (int j = 0; j < 2; ++j) {
        float s = 0.f, q = 0.f;
        #pragma unroll
        for (int i = 0; i < 4; ++i)
            #pragma unroll
            for (int r = 0; r < 4; ++r) {
                float v = acc[i][j][r] * W1INV;
                s += v; q += v * v;
                int row = m0 + mblk + i * 16 + lq * 4 + r;
                int col = n0 + nblk + j * 16 + lr;
                Xb[(size_t)row * LATENT + col] = f2bf(v);
            }
        // reduce over lq (lanes ^16, ^32): covers this wave's 64 rows
        s += __shfl_xor(s, 16, 64);  q += __shfl_xor(q, 16, 64);
        s += __shfl_xor(s, 32, 64);  q += __shfl_xor(q, 32, 64);
        if (lq == 0) {
            int col = n0 + nblk + j * 16 + lr;
            atomicAdd(&sums[half * LATENT + col], s);
            atomicAdd(&sumsqs[half * LATENT + col], q);
        }
    }
}

// ---------------------------------------------------------------------------
// GEMM2 split-K=4 with BN scale/shift computed in-block (LDS) and fused
// BN+ReLU on A-fragments. Partials stored as bf16.
// Zp[kc][m][n] = sum_{k in chunk} relu(X[m][k]*sc[k]+sh[k]) * W2[n][k]
// BM=128 x BN=64 x KC=512 -> 512 blocks.
// ---------------------------------------------------------------------------
__global__ __launch_bounds__(256) void gemm2_mfma(
    const unsigned short* __restrict__ Xb, const unsigned short* __restrict__ W2b,
    const float* __restrict__ sums, const float* __restrict__ sumsqs,
    const float* __restrict__ gamma, const float* __restrict__ beta,
    unsigned short* __restrict__ Zpb)
{
    __shared__ __align__(16) unsigned short As[128 * 32];
    __shared__ __align__(16) unsigned short Bs[64 * 32];
    __shared__ __align__(16) float scs[512];
    __shared__ __align__(16) float shs[512];
    const int tid = threadIdx.x;
    const int m0 = blockIdx.y * 128, n0 = blockIdx.x * 64, kc = blockIdx.z;
    const unsigned short* Ab = Xb + (size_t)m0 * LATENT + kc * 512;
    const unsigned short* Bb = W2b + (size_t)n0 * LATENT + kc * 512;
    const int half = m0 >> 11;
    // bn_final inline: this block's 512 scale/shift values
    #pragma unroll
    for (int u = 0; u < 2; ++u) {
        int e = u * 256 + tid;
        int col = kc * 512 + e;
        int g = half * LATENT + col;
        float mu  = sums[g] * (1.0f / BATCH);
        float var = sumsqs[g] * (1.0f / BATCH) - mu * mu;
        float sc = gamma[col] * rsqrtf(var + BN_EPS);
        scs[e] = sc;
        shs[e] = beta[col] - mu * sc;
    }
    const int wid = tid >> 6, lane = tid & 63;
    const int mblk = (wid >> 1) * 64, nblk = (wid & 1) * 32;
    const int lr = lane & 15, lk = lane >> 4;
    f32x4 zero = {0.f, 0.f, 0.f, 0.f};
    f32x4 acc[4][2];
    #pragma unroll
    for (int i = 0; i < 4; ++i) { acc[i][0] = zero; acc[i][1] = zero; }

    for (int k0 = 0; k0 < 512; k0 += 32) {
        __syncthreads();
        #pragma unroll
        for (int u = 0; u < 2; ++u) {
            int li = u * 256 + tid;
            int r = li >> 2, c = (li & 3) ^ ((li >> 3) & 3);
            gl_lds16(Ab + (size_t)r * LATENT + k0 + c * 8, As + li * 8);
        }
        {
            int li = tid;
            int r = li >> 2, c = (li & 3) ^ ((li >> 3) & 3);
            gl_lds16(Bb + (size_t)r * LATENT + k0 + c * 8, Bs + li * 8);
        }
        __syncthreads();
        // BN params for this lane's k-range (k0 + lk*8 .. +8), from LDS
        float4 sc0 = *reinterpret_cast<const float4*>(scs + k0 + lk * 8);
        float4 sc1 = *reinterpret_cast<const float4*>(scs + k0 + lk * 8 + 4);
        float4 sh0 = *reinterpret_cast<const float4*>(shs + k0 + lk * 8);
        float4 sh1 = *reinterpret_cast<const float4*>(shs + k0 + lk * 8 + 4);
        bf16x8 af[4], bv[2];
        #pragma unroll
        for (int i = 0; i < 4; ++i) {
            bf16x8 raw = *reinterpret_cast<const bf16x8*>(As + swz(mblk + i * 16 + lr, lk));
            bf16x8 a;
            a[0] = (__bf16)fmaxf(fmaf((float)raw[0], sc0.x, sh0.x), 0.f);
            a[1] = (__bf16)fmaxf(fmaf((float)raw[1], sc0.y, sh0.y), 0.f);
            a[2] = (__bf16)fmaxf(fmaf((float)raw[2], sc0.z, sh0.z), 0.f);
            a[3] = (__bf16)fmaxf(fmaf((float)raw[3], sc0.w, sh0.w), 0.f);
            a[4] = (__bf16)fmaxf(fmaf((float)raw[4], sc1.x, sh1.x), 0.f);
            a[5] = (__bf16)fmaxf(fmaf((float)raw[5], sc1.y, sh1.y), 0.f);
            a[6] = (__bf16)fmaxf(fmaf((float)raw[6], sc1.z, sh1.z), 0.f);
            a[7] = (__bf16)fmaxf(fmaf((float)raw[7], sc1.w, sh1.w), 0.f);
            af[i] = a;
        }
        #pragma unroll
        for (int j = 0; j < 2; ++j)
            bv[j] = *reinterpret_cast<const bf16x8*>(Bs + swz(nblk + j * 16 + lr, lk));
        #pragma unroll
        for (int i = 0; i < 4; ++i)
            #pragma unroll
            for (int j = 0; j < 2; ++j)
                acc[i][j] = __builtin_amdgcn_mfma_f32_16x16x32_bf16(af[i], bv[j], acc[i][j], 0, 0, 0);
    }

    unsigned short* Zk = Zpb + (size_t)kc * NROWS * PROJ;
    const int lq = lane >> 4;
    #pragma unroll
    for (int i = 0; i < 4; ++i)
        #pragma unroll
        for (int j = 0; j < 2; ++j)
            #pragma unroll
            for (int r = 0; r < 4; ++r) {
                int row = m0 + mblk + i * 16 + lq * 4 + r;
                int col = n0 + nblk + j * 16 + lr;
                Zk[(size_t)row * PROJ + col] = f2bf(acc[i][j][r]);
            }
}

// ---------------------------------------------------------------------------
// Sum 4 bf16 K-partials + b2, L2-normalize row -> bf16 ZNb. One wave per row.
// ---------------------------------------------------------------------------
__global__ __launch_bounds__(256) void rownorm_kernel(
    const unsigned short* __restrict__ Zpb, const float* __restrict__ b2,
    unsigned short* __restrict__ ZNb)
{
    const int wave = threadIdx.x >> 6;
    const int lane = threadIdx.x & 63;
    const int row = blockIdx.x * 4 + wave;
    float v[4];
    float sq = 0.f;
    #pragma unroll
    for (int i = 0; i < 4; ++i) {
        int col = lane + i * 64;
        float t = b2[col];
        #pragma unroll
        for (int c = 0; c < 4; ++c)
            t += bf2f(Zpb[(size_t)c * NROWS * PROJ + (size_t)row * PROJ + col]);
        v[i] = t;
        sq += t * t;
    }
    #pragma unroll
    for (int off = 32; off > 0; off >>= 1) sq += __shfl_xor(sq, off, 64);
    float inv = 1.0f / fmaxf(sqrtf(sq), COS_EPS);
    #pragma unroll
    for (int i = 0; i < 4; ++i)
        ZNb[(size_t)row * PROJ + lane + i * 64] = f2bf(v[i] * inv);
}

// ---------------------------------------------------------------------------
// sim tile via MFMA, upper-triangle tiles only (sim is symmetric; MFMA dot
// products are bitwise identical under operand swap). Off-diagonal tiles
// contribute row sums AND column sums to rowsum. Positive pairs write both.
// ---------------------------------------------------------------------------
__global__ __launch_bounds__(256) void simlse_mfma(
    const unsigned short* __restrict__ ZNb, float* __restrict__ rowsum,
    float* __restrict__ dgA, float* __restrict__ posA)
{
    if (blockIdx.x < blockIdx.y) return;   // symmetry: only tj >= ti
    __shared__ __align__(16) unsigned short As[128 * 32];
    __shared__ __align__(16) unsigned short Bs[128 * 32];
    const int tid = threadIdx.x;
    const int r0 = blockIdx.y * 128, j0 = blockIdx.x * 128;
    const bool offdiag = (j0 != r0);
    f32x4 zero = {0.f, 0.f, 0.f, 0.f};
    f32x4 acc[4][4];
    #pragma unroll
    for (int i = 0; i < 4; ++i)
        #pragma unroll
        for (int j = 0; j < 4; ++j) acc[i][j] = zero;
    mfma_loop<PROJ, PROJ, 4, 4>(ZNb + (size_t)r0 * PROJ, ZNb + (size_t)j0 * PROJ,
                                As, Bs, acc, tid);
    const int wid = tid >> 6, lane = tid & 63;
    const int mblk = (wid >> 1) * 64, nblk = (wid & 1) * 64;
    const int lr = lane & 15, lq = lane >> 4;
    float tcol[4] = {0.f, 0.f, 0.f, 0.f};
    #pragma unroll
    for (int i = 0; i < 4; ++i)
        #pragma unroll
        for (int r = 0; r < 4; ++r) {
            int R = r0 + mblk + i * 16 + lq * 4 + r;
            int P = (R < BATCH) ? R + BATCH : R - BATCH;
            float t = 0.f;
            #pragma unroll
            for (int j = 0; j < 4; ++j) {
                int J = j0 + nblk + j * 16 + lr;
                float s = acc[i][j][r] * TEMP_INV;
                float e = __expf(s);
                t += e;
                tcol[j] += e;
                if (J == R) dgA[R] = e;              // diag tiles only
                if (J == P) { posA[R] = s; posA[J] = s; }  // s[R,P]==s[P,R]
            }
            t += __shfl_xor(t, 1, 64);
            t += __shfl_xor(t, 2, 64);
            t += __shfl_xor(t, 4, 64);
            t += __shfl_xor(t, 8, 64);
            if (lr == 0) atomicAdd(&rowsum[R], t);
        }
    if (offdiag) {
        // column sums = the mirror tile's row sums (bitwise-identical terms)
        #pragma unroll
        for (int j = 0; j < 4; ++j) {
            float c = tcol[j];
            c += __shfl_xor(c, 16, 64);
            c += __shfl_xor(c, 32, 64);
            if (lq == 0) atomicAdd(&rowsum[j0 + nblk + j * 16 + lr], c);
        }
    }
}

// loss = (1/N) * sum_r [ log(rowsum_r - diag_r) - pos_r ]
__global__ __launch_bounds__(256) void loss_kernel(
    const float* __restrict__ rowsum, const float* __restrict__ dgA,
    const float* __restrict__ posA, float* __restrict__ out)
{
    __shared__ float red[256];
    float s = 0.f;
    for (int r = threadIdx.x; r < NROWS; r += 256)
        s += logf(rowsum[r] - dgA[r]) - posA[r];
    red[threadIdx.x] = s;
    __syncthreads();
    for (int off = 128; off > 0; off >>= 1) {
        if (threadIdx.x < off) red[threadIdx.x] += red[threadIdx.x + off];
        __syncthreads();
    }
    if (threadIdx.x == 0) out[0] = red[0] * (1.0f / NROWS);
}

// ---------------------------------------------------------------------------
extern "C" void kernel_launch(void* const* d_in, const int* in_sizes, int n_in,
                              void* d_out, int out_size, void* d_ws, size_t ws_size,
                              hipStream_t stream)
{
    const float* h_i   = (const float*)d_in[0];
    const float* h_j   = (const float*)d_in[1];
    const float* W1    = (const float*)d_in[2];
    const float* gamma = (const float*)d_in[3];
    const float* beta  = (const float*)d_in[4];
    const float* W2    = (const float*)d_in[5];
    const float* b2    = (const float*)d_in[6];
    float* out = (float*)d_out;

    // workspace (~40 MB)
    unsigned short* Zpb = (unsigned short*)d_ws;             // 4 * 4096*256 bf16
    float* sums   = (float*)(Zpb + (size_t)4 * NROWS * PROJ);// 4096
    float* sumsqs = sums + 2 * LATENT;                       // 4096
    float* rowsum = sumsqs + 2 * LATENT;                     // 4096
    float* dgA    = rowsum + NROWS;                          // 4096
    float* posA   = dgA + NROWS;                             // 4096
    unsigned char* Hq  = (unsigned char*)(posA + NROWS);     // 4096*2048 fp8
    unsigned char* W1q = Hq + (size_t)NROWS * LATENT;        // 2048*2048 fp8
    unsigned short* W2b = (unsigned short*)(W1q + (size_t)LATENT * LATENT); // 256*2048 bf16
    unsigned short* Xb  = W2b + (size_t)PROJ * LATENT;       // 4096*2048 bf16
    unsigned short* ZNb = Xb + (size_t)NROWS * LATENT;       // 4096*256 bf16

    // zero atomic accumulators (sums, sumsqs, rowsum contiguous = 12288 floats)
    hipMemsetAsync(sums, 0, (size_t)(4 * LATENT + NROWS) * sizeof(float), stream);

    cvt_all_kernel<<<(G4 + 255) / 256, 256, 0, stream>>>(h_i, h_j, W1, W2, Hq, W1q, W2b);
    gemm1_fp8<<<dim3(LATENT / 64, NROWS / 128), 256, 0, stream>>>(Hq, W1q, Xb, sums, sumsqs);
    gemm2_mfma<<<dim3(PROJ / 64, NROWS / 128, 4), 256, 0, stream>>>(Xb, W2b, sums, sumsqs, gamma, beta, Zpb);
    rownorm_kernel<<<NROWS / 4, 256, 0, stream>>>(Zpb, b2, ZNb);
    simlse_mfma<<<dim3(NROWS / 128, NROWS / 128), 256, 0, stream>>>(ZNb, rowsum, dgA, posA);
    loss_kernel<<<1, 256, 0, stream>>>(rowsum, dgA, posA, out);
}

// Round 10
// 173.273 us; speedup vs baseline: 1.2364x; 1.0159x over previous
//
#include <hip/hip_runtime.h>
#include <hip/hip_fp8.h>
#include <math.h>

#define BATCH   2048
#define NROWS   4096   // 2*BATCH
#define LATENT  2048
#define PROJ    256
#define BN_EPS  1e-5f
#define COS_EPS 1e-8f
#define W1SCALE 32.0f      // W1/W2 pre-scaled into e4m3 normal range
#define W1INV   (1.0f / 32.0f)
#define ZNSCALE 16.0f      // zn components ~N(0,1/16) -> x16 for e4m3
// sim s = 2*cos; dotq = (16 zi)·(16 zj) = 256 cos -> s = dotq / 128
#define SIMSCALE (1.0f / 128.0f)

typedef float f32x4 __attribute__((ext_vector_type(4)));
typedef long  i64;

__device__ __forceinline__ unsigned short f2bf(float f) {
    union { float f; unsigned int u; } c; c.f = f;
    return (unsigned short)((c.u + 0x7FFFu + ((c.u >> 16) & 1u)) >> 16);
}
__device__ __forceinline__ float bf2f(unsigned short h) {
    union { unsigned int u; float f; } c; c.u = ((unsigned int)h) << 16;
    return c.f;
}
__device__ __forceinline__ unsigned char f2fp8(float f) {
    __hip_fp8_e4m3 t(f);
    return (unsigned char)t.__x;
}
__device__ __forceinline__ float fp82f(unsigned char b) {
    __hip_fp8_e4m3 t; t.__x = b;
    return (float)t;
}

// async global->LDS, 16 bytes per lane. LDS dest is wave-uniform base + lane*16.
__device__ __forceinline__ void gl_lds16(const void* g, void* l) {
    __builtin_amdgcn_global_load_lds(
        (const __attribute__((address_space(1))) void*)g,
        (__attribute__((address_space(3))) void*)l, 16, 0, 0);
}

// fp8 BK=128 granule swizzle (8 slots of 16B per row)
__device__ __forceinline__ int mix8(int R) {
    return (R & 7) ^ ((R >> 1) & 4);
}

// ---------------------------------------------------------------------------
// Fused convert: h_i,h_j -> fp8 Hq; W1 -> fp8*32 W1q; W2 -> fp8*32 W2q.
// Block 0 additionally zeroes the atomic accumulators (sums/sumsqs/rowsum).
// ---------------------------------------------------------------------------
#define G1 1048576   // h_i float4-groups
#define G2 2097152
#define G3 3145728
#define G4 3276800
__global__ __launch_bounds__(256) void cvt_all_kernel(
    const float* __restrict__ h_i, const float* __restrict__ h_j,
    const float* __restrict__ W1,  const float* __restrict__ W2,
    unsigned char* __restrict__ Hq, unsigned char* __restrict__ W1q,
    unsigned char* __restrict__ W2q, float* __restrict__ zeroacc)
{
    int i = blockIdx.x * 256 + threadIdx.x;
    if (blockIdx.x == 0) {
        #pragma unroll
        for (int u = 0; u < 48; ++u) zeroacc[u * 256 + threadIdx.x] = 0.f;   // 12288 floats
    }
    if (i >= G4) return;
    if (i < G2) {
        const float* src = (i < G1) ? h_i : h_j;
        int off = (i < G1) ? i : i - G1;
        float4 v = reinterpret_cast<const float4*>(src)[off];
        uchar4 o;
        o.x = f2fp8(v.x); o.y = f2fp8(v.y); o.z = f2fp8(v.z); o.w = f2fp8(v.w);
        reinterpret_cast<uchar4*>(Hq)[i] = o;
    } else if (i < G3) {
        int off = i - G2;
        float4 v = reinterpret_cast<const float4*>(W1)[off];
        uchar4 o;
        o.x = f2fp8(v.x * W1SCALE); o.y = f2fp8(v.y * W1SCALE);
        o.z = f2fp8(v.z * W1SCALE); o.w = f2fp8(v.w * W1SCALE);
        reinterpret_cast<uchar4*>(W1q)[off] = o;
    } else {
        int off = i - G3;
        float4 v = reinterpret_cast<const float4*>(W2)[off];
        uchar4 o;
        o.x = f2fp8(v.x * W1SCALE); o.y = f2fp8(v.y * W1SCALE);
        o.z = f2fp8(v.z * W1SCALE); o.w = f2fp8(v.w * W1SCALE);
        reinterpret_cast<uchar4*>(W2q)[off] = o;
    }
}

// ---------------------------------------------------------------------------
// fp8 MFMA K-loop: BM=128, BN=64, BK=128. acc[4][2]. 4 waves in 2x2.
// ---------------------------------------------------------------------------
template<int KSTRIDE, int KLEN>
__device__ __forceinline__ void fp8_loop(
    const unsigned char* __restrict__ Ab, const unsigned char* __restrict__ Bb,
    unsigned char* As, unsigned char* Bs, f32x4 acc[4][2], int tid)
{
    const int wid = tid >> 6, lane = tid & 63;
    const int mblk = (wid >> 1) * 64, nblk = (wid & 1) * 32;
    const int lr = lane & 15, lk = lane >> 4;
    for (int k0 = 0; k0 < KLEN; k0 += 128) {
        __syncthreads();
        #pragma unroll
        for (int u = 0; u < 4; ++u) {
            int li = u * 256 + tid;
            int r = li >> 3, s = li & 7;
            gl_lds16(Ab + (size_t)r * KSTRIDE + k0 + ((s ^ mix8(r)) * 16), As + li * 16);
        }
        #pragma unroll
        for (int u = 0; u < 2; ++u) {
            int li = u * 256 + tid;
            int r = li >> 3, s = li & 7;
            gl_lds16(Bb + (size_t)r * KSTRIDE + k0 + ((s ^ mix8(r)) * 16), Bs + li * 16);
        }
        __syncthreads();
        i64 af[4][4], bv[2][4];
        #pragma unroll
        for (int i = 0; i < 4; ++i) {
            int R = mblk + i * 16 + lr;
            int mr = mix8(R);
            int base = R * 128 + (lk & 1) * 8;
            #pragma unroll
            for (int t = 0; t < 4; ++t) {
                int g = 2 * t + (lk >> 1);
                af[i][t] = *reinterpret_cast<const i64*>(As + base + ((g ^ mr) << 4));
            }
        }
        #pragma unroll
        for (int j = 0; j < 2; ++j) {
            int R = nblk + j * 16 + lr;
            int mr = mix8(R);
            int base = R * 128 + (lk & 1) * 8;
            #pragma unroll
            for (int t = 0; t < 4; ++t) {
                int g = 2 * t + (lk >> 1);
                bv[j][t] = *reinterpret_cast<const i64*>(Bs + base + ((g ^ mr) << 4));
            }
        }
        #pragma unroll
        for (int t = 0; t < 4; ++t)
            #pragma unroll
            for (int i = 0; i < 4; ++i)
                #pragma unroll
                for (int j = 0; j < 2; ++j)
                    acc[i][j] = __builtin_amdgcn_mfma_f32_16x16x32_fp8_fp8(
                        af[i][t], bv[j][t], acc[i][j], 0, 0, 0);
    }
}

// ---------------------------------------------------------------------------
// GEMM1 (fp8): X[m][n] = sum_k H[m][k]*W1[n][k]  (4096x2048x2048)
// BM=128 x BN=64 -> 1024 blocks (4/CU). Epilogue: raw-X fp8 store + BN stats.
// ---------------------------------------------------------------------------
__global__ __launch_bounds__(256, 4) void gemm1_fp8(
    const unsigned char* __restrict__ Hq, const unsigned char* __restrict__ W1q,
    unsigned char* __restrict__ Xq, float* __restrict__ sums, float* __restrict__ sumsqs)
{
    __shared__ __align__(16) unsigned char As[128 * 128];
    __shared__ __align__(16) unsigned char Bs[64 * 128];
    const int tid = threadIdx.x;
    const int m0 = blockIdx.y * 128, n0 = blockIdx.x * 64;
    f32x4 zero = {0.f, 0.f, 0.f, 0.f};
    f32x4 acc[4][2];
    #pragma unroll
    for (int i = 0; i < 4; ++i) { acc[i][0] = zero; acc[i][1] = zero; }
    fp8_loop<LATENT, LATENT>(Hq + (size_t)m0 * LATENT, W1q + (size_t)n0 * LATENT,
                             As, Bs, acc, tid);
    const int wid = tid >> 6, lane = tid & 63;
    const int mblk = (wid >> 1) * 64, nblk = (wid & 1) * 32;
    const int lr = lane & 15, lq = lane >> 4;
    const int half = m0 >> 11;
    #pragma unroll
    for (int j = 0; j < 2; ++j) {
        float s = 0.f, q = 0.f;
        #pragma unroll
        for (int i = 0; i < 4; ++i)
            #pragma unroll
            for (int r = 0; r < 4; ++r) {
                float v = acc[i][j][r] * W1INV;
                s += v; q += v * v;
                int row = m0 + mblk + i * 16 + lq * 4 + r;
                int col = n0 + nblk + j * 16 + lr;
                Xq[(size_t)row * LATENT + col] = f2fp8(v);   // raw X, ~N(0,1)
            }
        s += __shfl_xor(s, 16, 64);  q += __shfl_xor(q, 16, 64);
        s += __shfl_xor(s, 32, 64);  q += __shfl_xor(q, 32, 64);
        if (lq == 0) {
            int col = n0 + nblk + j * 16 + lr;
            atomicAdd(&sums[half * LATENT + col], s);
            atomicAdd(&sumsqs[half * LATENT + col], q);
        }
    }
}

// ---------------------------------------------------------------------------
// BN+ReLU in-place on fp8 X (scale/shift from stats, applied once per elem).
// One block per row, 8 elems/thread.
// ---------------------------------------------------------------------------
__global__ __launch_bounds__(256) void bnrelu8_kernel(
    unsigned char* __restrict__ Xq, const float* __restrict__ sums,
    const float* __restrict__ sumsqs, const float* __restrict__ gamma,
    const float* __restrict__ beta)
{
    const int row = blockIdx.x;
    const int half = row >> 11;
    const int col = threadIdx.x * 8;
    size_t idx = (size_t)row * LATENT + col;
    uchar4 a = *reinterpret_cast<const uchar4*>(Xq + idx);
    uchar4 b = *reinterpret_cast<const uchar4*>(Xq + idx + 4);
    uchar4 oa, ob;
    #pragma unroll
    for (int u = 0; u < 8; ++u) {
        int c = col + u;
        int g = half * LATENT + c;
        float mu  = sums[g] * (1.0f / BATCH);
        float var = sumsqs[g] * (1.0f / BATCH) - mu * mu;
        float sc = gamma[c] * rsqrtf(var + BN_EPS);
        float sh = beta[c] - mu * sc;
        unsigned char x = (u < 4) ? ((const unsigned char*)&a)[u] : ((const unsigned char*)&b)[u - 4];
        unsigned char o = f2fp8(fmaxf(fmaf(fp82f(x), sc, sh), 0.f));
        if (u < 4) ((unsigned char*)&oa)[u] = o; else ((unsigned char*)&ob)[u - 4] = o;
    }
    *reinterpret_cast<uchar4*>(Xq + idx) = oa;
    *reinterpret_cast<uchar4*>(Xq + idx + 4) = ob;
}

// ---------------------------------------------------------------------------
// GEMM2 (fp8) split-K=4: Zpb[kc][m][n] = sum_{k in chunk} Xq[m][k]*W2q[n][k]
// BM=128 x BN=64 x KC=512 -> 512 blocks. Partials bf16 (x 1/32).
// ---------------------------------------------------------------------------
__global__ __launch_bounds__(256, 4) void gemm2_fp8(
    const unsigned char* __restrict__ Xq, const unsigned char* __restrict__ W2q,
    unsigned short* __restrict__ Zpb)
{
    __shared__ __align__(16) unsigned char As[128 * 128];
    __shared__ __align__(16) unsigned char Bs[64 * 128];
    const int tid = threadIdx.x;
    const int m0 = blockIdx.y * 128, n0 = blockIdx.x * 64, kc = blockIdx.z;
    f32x4 zero = {0.f, 0.f, 0.f, 0.f};
    f32x4 acc[4][2];
    #pragma unroll
    for (int i = 0; i < 4; ++i) { acc[i][0] = zero; acc[i][1] = zero; }
    fp8_loop<LATENT, 512>(Xq + (size_t)m0 * LATENT + kc * 512,
                          W2q + (size_t)n0 * LATENT + kc * 512, As, Bs, acc, tid);
    unsigned short* Zk = Zpb + (size_t)kc * NROWS * PROJ;
    const int wid = tid >> 6, lane = tid & 63;
    const int mblk = (wid >> 1) * 64, nblk = (wid & 1) * 32;
    const int lr = lane & 15, lq = lane >> 4;
    #pragma unroll
    for (int i = 0; i < 4; ++i)
        #pragma unroll
        for (int j = 0; j < 2; ++j)
            #pragma unroll
            for (int r = 0; r < 4; ++r) {
                int row = m0 + mblk + i * 16 + lq * 4 + r;
                int col = n0 + nblk + j * 16 + lr;
                Zk[(size_t)row * PROJ + col] = f2bf(acc[i][j][r] * W1INV);
            }
}

// ---------------------------------------------------------------------------
// Sum 4 bf16 K-partials + b2, L2-normalize -> fp8 ZNq (zn*16). 1 wave/row.
// ---------------------------------------------------------------------------
__global__ __launch_bounds__(256) void rownorm_kernel(
    const unsigned short* __restrict__ Zpb, const float* __restrict__ b2,
    unsigned char* __restrict__ ZNq)
{
    const int wave = threadIdx.x >> 6;
    const int lane = threadIdx.x & 63;
    const int row = blockIdx.x * 4 + wave;
    float v[4];
    float sq = 0.f;
    #pragma unroll
    for (int i = 0; i < 4; ++i) {
        int col = lane + i * 64;
        float t = b2[col];
        #pragma unroll
        for (int c = 0; c < 4; ++c)
            t += bf2f(Zpb[(size_t)c * NROWS * PROJ + (size_t)row * PROJ + col]);
        v[i] = t;
        sq += t * t;
    }
    #pragma unroll
    for (int off = 32; off > 0; off >>= 1) sq += __shfl_xor(sq, off, 64);
    float inv = ZNSCALE / fmaxf(sqrtf(sq), COS_EPS);
    #pragma unroll
    for (int i = 0; i < 4; ++i)
        ZNq[(size_t)row * PROJ + lane + i * 64] = f2fp8(v[i] * inv);
}

// ---------------------------------------------------------------------------
// sim tiles (fp8), upper-triangle only, K=256 staged in ONE shot (1 barrier).
// 128x128 tile; As/Bs 32 KB each (16-slot granule XOR swizzle).
// Off-diag tiles contribute row AND column sums (bitwise-identical mirror).
// ---------------------------------------------------------------------------
__global__ __launch_bounds__(256) void simlse_fp8(
    const unsigned char* __restrict__ ZNq, float* __restrict__ rowsum,
    float* __restrict__ dgA, float* __restrict__ posA)
{
    if (blockIdx.x < blockIdx.y) return;   // symmetry: only tj >= ti
    __shared__ __align__(16) unsigned char As[128 * 256];
    __shared__ __align__(16) unsigned char Bs[128 * 256];
    const int tid = threadIdx.x;
    const int r0 = blockIdx.y * 128, j0 = blockIdx.x * 128;
    const bool offdiag = (j0 != r0);
    const unsigned char* Ab = ZNq + (size_t)r0 * PROJ;
    const unsigned char* Bb = ZNq + (size_t)j0 * PROJ;
    // stage both panels fully: 8 granules/thread/operand, slot = c ^ (r&15)
    #pragma unroll
    for (int u = 0; u < 8; ++u) {
        int li = u * 256 + tid;
        int r = li >> 4, s = li & 15;
        int c = s ^ (r & 15);
        gl_lds16(Ab + (size_t)r * PROJ + c * 16, As + li * 16);
    }
    #pragma unroll
    for (int u = 0; u < 8; ++u) {
        int li = u * 256 + tid;
        int r = li >> 4, s = li & 15;
        int c = s ^ (r & 15);
        gl_lds16(Bb + (size_t)r * PROJ + c * 16, Bs + li * 16);
    }
    __syncthreads();
    const int wid = tid >> 6, lane = tid & 63;
    const int mblk = (wid >> 1) * 64, nblk = (wid & 1) * 64;
    const int lr = lane & 15, lk = lane >> 4;
    f32x4 zero = {0.f, 0.f, 0.f, 0.f};
    f32x4 acc[4][4];
    #pragma unroll
    for (int i = 0; i < 4; ++i)
        #pragma unroll
        for (int j = 0; j < 4; ++j) acc[i][j] = zero;
    #pragma unroll
    for (int t = 0; t < 8; ++t) {
        int g = 2 * t + (lk >> 1);
        i64 af[4], bv[4];
        #pragma unroll
        for (int i = 0; i < 4; ++i) {
            int R = mblk + i * 16 + lr;
            af[i] = *reinterpret_cast<const i64*>(As + R * 256 + ((g ^ (R & 15)) << 4) + (lk & 1) * 8);
        }
        #pragma unroll
        for (int j = 0; j < 4; ++j) {
            int R = nblk + j * 16 + lr;
            bv[j] = *reinterpret_cast<const i64*>(Bs + R * 256 + ((g ^ (R & 15)) << 4) + (lk & 1) * 8);
        }
        #pragma unroll
        for (int i = 0; i < 4; ++i)
            #pragma unroll
            for (int j = 0; j < 4; ++j)
                acc[i][j] = __builtin_amdgcn_mfma_f32_16x16x32_fp8_fp8(af[i], bv[j], acc[i][j], 0, 0, 0);
    }
    const int lq = lane >> 4;
    float tcol[4] = {0.f, 0.f, 0.f, 0.f};
    #pragma unroll
    for (int i = 0; i < 4; ++i)
        #pragma unroll
        for (int r = 0; r < 4; ++r) {
            int R = r0 + mblk + i * 16 + lq * 4 + r;
            int P = (R < BATCH) ? R + BATCH : R - BATCH;
            float t = 0.f;
            #pragma unroll
            for (int j = 0; j < 4; ++j) {
                int J = j0 + nblk + j * 16 + lr;
                float s = acc[i][j][r] * SIMSCALE;
                float e = __expf(s);
                t += e;
                tcol[j] += e;
                if (J == R) dgA[R] = e;                    // diag tiles only
                if (J == P) { posA[R] = s; posA[J] = s; }  // s[R,P]==s[P,R]
            }
            t += __shfl_xor(t, 1, 64);
            t += __shfl_xor(t, 2, 64);
            t += __shfl_xor(t, 4, 64);
            t += __shfl_xor(t, 8, 64);
            if (lr == 0) atomicAdd(&rowsum[R], t);
        }
    if (offdiag) {
        #pragma unroll
        for (int j = 0; j < 4; ++j) {
            float c = tcol[j];
            c += __shfl_xor(c, 16, 64);
            c += __shfl_xor(c, 32, 64);
            if (lq == 0) atomicAdd(&rowsum[j0 + nblk + j * 16 + lr], c);
        }
    }
}

// loss = (1/N) * sum_r [ log(rowsum_r - diag_r) - pos_r ]
__global__ __launch_bounds__(256) void loss_kernel(
    const float* __restrict__ rowsum, const float* __restrict__ dgA,
    const float* __restrict__ posA, float* __restrict__ out)
{
    __shared__ float red[256];
    float s = 0.f;
    for (int r = threadIdx.x; r < NROWS; r += 256)
        s += logf(rowsum[r] - dgA[r]) - posA[r];
    red[threadIdx.x] = s;
    __syncthreads();
    for (int off = 128; off > 0; off >>= 1) {
        if (threadIdx.x < off) red[threadIdx.x] += red[threadIdx.x + off];
        __syncthreads();
    }
    if (threadIdx.x == 0) out[0] = red[0] * (1.0f / NROWS);
}

// ---------------------------------------------------------------------------
extern "C" void kernel_launch(void* const* d_in, const int* in_sizes, int n_in,
                              void* d_out, int out_size, void* d_ws, size_t ws_size,
                              hipStream_t stream)
{
    const float* h_i   = (const float*)d_in[0];
    const float* h_j   = (const float*)d_in[1];
    const float* W1    = (const float*)d_in[2];
    const float* gamma = (const float*)d_in[3];
    const float* beta  = (const float*)d_in[4];
    const float* W2    = (const float*)d_in[5];
    const float* b2    = (const float*)d_in[6];
    float* out = (float*)d_out;

    // workspace (~31 MB)
    unsigned short* Zpb = (unsigned short*)d_ws;             // 4 * 4096*256 bf16
    float* sums   = (float*)(Zpb + (size_t)4 * NROWS * PROJ);// 4096
    float* sumsqs = sums + 2 * LATENT;                       // 4096
    float* rowsum = sumsqs + 2 * LATENT;                     // 4096 (zeroed w/ stats)
    float* dgA    = rowsum + NROWS;                          // 4096
    float* posA   = dgA + NROWS;                             // 4096
    unsigned char* Hq  = (unsigned char*)(posA + NROWS);     // 4096*2048 fp8
    unsigned char* W1q = Hq + (size_t)NROWS * LATENT;        // 2048*2048 fp8
    unsigned char* W2q = W1q + (size_t)LATENT * LATENT;      // 256*2048 fp8
    unsigned char* Xq  = W2q + (size_t)PROJ * LATENT;        // 4096*2048 fp8
    unsigned char* ZNq = Xq + (size_t)NROWS * LATENT;        // 4096*256 fp8

    cvt_all_kernel<<<(G4 + 255) / 256, 256, 0, stream>>>(h_i, h_j, W1, W2, Hq, W1q, W2q, sums);
    gemm1_fp8<<<dim3(LATENT / 64, NROWS / 128), 256, 0, stream>>>(Hq, W1q, Xq, sums, sumsqs);
    bnrelu8_kernel<<<NROWS, 256, 0, stream>>>(Xq, sums, sumsqs, gamma, beta);
    gemm2_fp8<<<dim3(PROJ / 64, NROWS / 128, 4), 256, 0, stream>>>(Xq, W2q, Zpb);
    rownorm_kernel<<<NROWS / 4, 256, 0, stream>>>(Zpb, b2, ZNq);
    simlse_fp8<<<dim3(NROWS / 128, NROWS / 128), 256, 0, stream>>>(ZNq, rowsum, dgA, posA);
    loss_kernel<<<1, 256, 0, stream>>>(rowsum, dgA, posA, out);
}